// Round 15
// baseline (323.277 us; speedup 1.0000x reference)
//
#include <hip/hip_runtime.h>
#include <hip/hip_bf16.h>

#define BB 4
#define KK 16
#define NN 50000
#define EE 300000
#define RR 64
#define ERE 2048
#define RT 4
#define DD 64
#define LL 4
#define FCAP 256
#define NSB 196   // (NN+255)/256
#define NFB 1568  // bitmap ints, >= (NN+31)/32

typedef short s16x8 __attribute__((ext_vector_type(8)));
typedef float f32x4 __attribute__((ext_vector_type(4)));

__device__ __forceinline__ float wsum64(float v) {
#pragma unroll
    for (int off = 32; off > 0; off >>= 1) v += __shfl_xor(v, off, 64);
    return v;
}

__device__ __forceinline__ unsigned short f2bf_rne(float f) {
    unsigned u = __builtin_bit_cast(unsigned, f);
    return (unsigned short)((u + 0x7FFFu + ((u >> 16) & 1u)) >> 16);
}

__device__ __forceinline__ float bf2f(unsigned short h) {
    unsigned u = ((unsigned)h) << 16;
    return __builtin_bit_cast(float, u);
}

// ==================== fused edge pass: histogram + fixlist + fix bitmap ======
__global__ __launch_bounds__(256) void edge_scan(
    const int* __restrict__ edge_index, const int* __restrict__ edge_type,
    const int* __restrict__ bt, int* __restrict__ deg,
    int* __restrict__ fixlist, int* __restrict__ cnt,
    unsigned* __restrict__ fixbit)
{
    int e = blockIdx.x * 256 + threadIdx.x;
    if (e < BB) {
        int h0 = bt[e * KK * 3];
        int pos = atomicAdd(&cnt[e], 1);
        if (pos < FCAP) fixlist[e * FCAP + pos] = h0 | (int)(0xFFFFu << 16);
        atomicOr(&fixbit[h0 >> 5], 1u << (h0 & 31));
    }
    if (e >= EE) return;
    int s = edge_index[e];
    int d = edge_index[EE + e];
    int t = edge_type[e];
    atomicAdd(&deg[d], 1);
#pragma unroll
    for (int b = 0; b < BB; ++b) {
        int h0 = bt[b * KK * 3];
        if (s == h0) {
            int pos = atomicAdd(&cnt[b], 1);
            if (pos < FCAP) fixlist[b * FCAP + pos] = d | (t << 16);
            atomicOr(&fixbit[d >> 5], 1u << (d & 31));
        }
    }
}

// ==================== scan pipeline ==========================================
__global__ __launch_bounds__(256) void scan_a(
    const int* __restrict__ deg, int* __restrict__ bsum)
{
    int i = blockIdx.x * 256 + threadIdx.x;
    int v = (i < NN) ? deg[i] : 0;
    int s = v;
#pragma unroll
    for (int off = 32; off > 0; off >>= 1) s += __shfl_xor(s, off, 64);
    __shared__ int ls[4];
    if ((threadIdx.x & 63) == 0) ls[threadIdx.x >> 6] = s;
    __syncthreads();
    if (threadIdx.x == 0) bsum[blockIdx.x] = ls[0] + ls[1] + ls[2] + ls[3];
}

__global__ __launch_bounds__(256) void setup_small(
    const int* __restrict__ bsum, int* __restrict__ boff, int* __restrict__ rowptr,
    const int* __restrict__ rel_edge_index, const int* __restrict__ rel_edge_type,
    int* __restrict__ rptr, int* __restrict__ rpack,
    const float* __restrict__ entW, unsigned short* __restrict__ wbf)
{
    int t = threadIdx.x;
    if (blockIdx.x == 0) {
        __shared__ int tmp[256];
        int v = (t < NSB) ? bsum[t] : 0;
        tmp[t] = v;
        __syncthreads();
        for (int off = 1; off < 256; off <<= 1) {
            int u = (t >= off) ? tmp[t - off] : 0;
            __syncthreads();
            tmp[t] += u;
            __syncthreads();
        }
        if (t < NSB) boff[t] = tmp[t] - v;
        if (t == 0) rowptr[NN] = EE;
    } else if (blockIdx.x == 1) {
        __shared__ int hdeg[RR];
        __shared__ int hcur[RR];
        if (t < RR) hdeg[t] = 0;
        __syncthreads();
        for (int e = t; e < ERE; e += 256) atomicAdd(&hdeg[rel_edge_index[ERE + e]], 1);
        __syncthreads();
        if (t == 0) {
            int run = 0;
            for (int r = 0; r < RR; ++r) { hcur[r] = run; rptr[r] = run; run += hdeg[r]; }
            rptr[RR] = run;
        }
        __syncthreads();
        for (int e = t; e < ERE; e += 256) {
            int s = rel_edge_index[e];
            int d = rel_edge_index[ERE + e];
            int ty = rel_edge_type[e];
            int pos = atomicAdd(&hcur[d], 1);
            rpack[pos] = s | (ty << 16);
        }
    } else {
        if (t >= 64) return;
        int blk = blockIdx.x - 2;        // li*16 + tt*4 + s
        int li = blk >> 4;
        int tt = (blk >> 2) & 3, s = blk & 3;
        const float* W = entW + (li + 1) * 2 * DD * DD;
        unsigned short* dst = wbf + ((size_t)blk * 64 + t) * 8;
#pragma unroll
        for (int j = 0; j < 8; ++j) {
            int k = s * 32 + (t >> 4) * 8 + j;
            int n = tt * 16 + (t & 15);
            dst[j] = f2bf_rne(W[k * DD + n]);
        }
    }
}

__global__ __launch_bounds__(256) void scan_c(
    const int* __restrict__ deg, const int* __restrict__ boff,
    int* __restrict__ rowptr, int* __restrict__ cursor)
{
    __shared__ int tmp[256];
    int t = threadIdx.x;
    int i = blockIdx.x * 256 + t;
    int v = (i < NN) ? deg[i] : 0;
    tmp[t] = v;
    __syncthreads();
    for (int off = 1; off < 256; off <<= 1) {
        int u = (t >= off) ? tmp[t - off] : 0;
        __syncthreads();
        tmp[t] += u;
        __syncthreads();
    }
    if (i < NN) {
        int excl = tmp[t] - v + boff[blockIdx.x];
        rowptr[i] = excl;
        cursor[i] = excl;
    }
}

__global__ __launch_bounds__(256) void csr_fill(
    const int* __restrict__ edge_index, const int* __restrict__ edge_type,
    int* __restrict__ cursor, int* __restrict__ pack)
{
    int e = blockIdx.x * 256 + threadIdx.x;
    if (e >= EE) return;
    int s = edge_index[e];
    int d = edge_index[EE + e];
    int t = edge_type[e];
    int pos = atomicAdd(&cursor[d], 1);
    pack[pos] = s | (t << 16);  // src < 2^16, et < 64
}

// ==================== relation stage =========================================
__global__ __launch_bounds__(256) void rel_layer0(
    const int* __restrict__ rptr, const int* __restrict__ rpack,
    const int* __restrict__ bt, const float* __restrict__ emb,
    const float* __restrict__ W, const float* __restrict__ bias,
    const float* __restrict__ g, const float* __restrict__ beta,
    float* __restrict__ xout)
{
    int row = blockIdx.x * 4 + (int)(threadIdx.x >> 6);  // 0..BB*RR-1
    int lane = threadIdx.x & 63;
    int b = row >> 6, r = row & 63;
    int r0 = bt[(b * KK) * 3 + 2];
    int beg = rptr[r], end = rptr[r + 1];
    float av = (r == r0) ? 1.0f : 0.0f;
    for (int j = beg; j < end; ++j) {
        int p = rpack[j];
        if ((p & 0xFFFF) == r0) av += emb[(p >> 16) * DD + lane];
    }
    float xv = (r == r0) ? 1.0f : 0.0f;
    float acc = bias[lane];
#pragma unroll 8
    for (int k = 0; k < DD; ++k) {
        acc += __shfl(xv, k, 64) * W[k * DD + lane];
        acc += __shfl(av, k, 64) * W[(DD + k) * DD + lane];
    }
    float m = wsum64(acc) * (1.0f / DD);
    float c = acc - m;
    float v = wsum64(c * c) * (1.0f / DD);
    float o = c * rsqrtf(v + 1e-5f) * g[lane] + beta[lane];
    xout[row * DD + lane] = fmaxf(o, 0.0f) + xv;
}

__global__ __launch_bounds__(256) void rel_layer(
    const int* __restrict__ rptr, const int* __restrict__ rpack,
    const int* __restrict__ bt, const float* __restrict__ emb,
    const float* __restrict__ W, const float* __restrict__ bias,
    const float* __restrict__ g, const float* __restrict__ beta,
    const float* __restrict__ xin, float* __restrict__ xout)
{
    int row = blockIdx.x * 4 + (int)(threadIdx.x >> 6);  // 0..BB*RR-1
    int lane = threadIdx.x & 63;
    int b = row >> 6, r = row & 63;
    int r0 = bt[(b * KK) * 3 + 2];
    int beg = rptr[r], end = rptr[r + 1];
    const float* xb = xin + b * RR * DD;
    float av = (r == r0) ? 1.0f : 0.0f;
    for (int j = beg; j < end; ++j) {
        int p = rpack[j];
        av += xb[(p & 0xFFFF) * DD + lane] * emb[(p >> 16) * DD + lane];
    }
    float xv = xin[row * DD + lane];
    float acc = bias[lane];
#pragma unroll 8
    for (int k = 0; k < DD; ++k) {
        acc += __shfl(xv, k, 64) * W[k * DD + lane];
        acc += __shfl(av, k, 64) * W[(DD + k) * DD + lane];
    }
    float m = wsum64(acc) * (1.0f / DD);
    float c = acc - m;
    float v = wsum64(c * c) * (1.0f / DD);
    float o = c * rsqrtf(v + 1e-5f) * g[lane] + beta[lane];
    xout[row * DD + lane] = fmaxf(o, 0.0f) + xv;
}

// all-4-layer projection + query extraction (block 0)
__global__ __launch_bounds__(256) void rel_projq(
    const float* __restrict__ rel_repr, const int* __restrict__ bt,
    const float* __restrict__ W1, const float* __restrict__ b1,
    const float* __restrict__ W2, const float* __restrict__ b2,
    float* __restrict__ rel_buf4, float* __restrict__ query)
{
    int grow = blockIdx.x * 4 + (int)(threadIdx.x >> 6);  // 0..4*B*R-1
    int lane = threadIdx.x & 63;
    int l = grow / (BB * RR);
    int row = grow - l * (BB * RR);
    const float* xr = &rel_repr[row * DD];
    const float* w1 = W1 + l * DD * DD;
    const float* w2 = W2 + l * DD * DD;
    float h = b1[l * DD + lane];
#pragma unroll 8
    for (int k = 0; k < DD; ++k) h += xr[k] * w1[k * DD + lane];
    h = fmaxf(h, 0.0f);
    float o = b2[l * DD + lane];
#pragma unroll 8
    for (int k = 0; k < DD; ++k) o += __shfl(h, k, 64) * w2[k * DD + lane];
    rel_buf4[grow * DD + lane] = o;
    if (blockIdx.x == 0) {
        int i = threadIdx.x;  // 0..255 = B*D
        int b = i / DD, d = i - b * DD;
        int r0 = bt[(b * KK) * 3 + 2];
        query[b * DD + d] = rel_repr[(b * RR + r0) * DD + d];
    }
}

// ==================== entity stage ===========================================
// seed the union-fixset rows of x_bfiA with dvec (bf16 of LN(bias) default)
__global__ __launch_bounds__(256) void l0_seed(
    const int* __restrict__ fixlist, const int* __restrict__ cnt,
    const float* __restrict__ b0, const float* __restrict__ g0,
    const float* __restrict__ be0, unsigned short* __restrict__ x_bfi)
{
    int gidx = blockIdx.x * 4 + (int)(threadIdx.x >> 6);  // (bl, i)
    int lane = threadIdx.x & 63;
    float bv = b0[lane];
    float m = wsum64(bv) * (1.0f / DD);
    float c = bv - m;
    float v = wsum64(c * c) * (1.0f / DD);
    float dvec = fmaxf(c * rsqrtf(v + 1e-5f) * g0[lane] + be0[lane], 0.0f);
    int bl = gidx / FCAP, i = gidx - bl * FCAP;
    int nc = min(cnt[bl], FCAP);
    if (i >= nc) return;
    int vx = fixlist[bl * FCAP + i] & 0xFFFF;
    int b = lane >> 4, d0 = (lane & 15) * 4;
    ushort4 o;
    o.x = f2bf_rne(__shfl(dvec, d0 + 0, 64));
    o.y = f2bf_rne(__shfl(dvec, d0 + 1, 64));
    o.z = f2bf_rne(__shfl(dvec, d0 + 2, 64));
    o.w = f2bf_rne(__shfl(dvec, d0 + 3, 64));
    *(ushort4*)&x_bfi[((size_t)vx * BB + b) * DD + d0] = o;
}

__global__ __launch_bounds__(256) void l0_fix(
    const int* __restrict__ bt, const int* __restrict__ fixlist,
    const int* __restrict__ cnt, const float* __restrict__ query,
    const float* __restrict__ rel_buf,
    const float* __restrict__ W0, const float* __restrict__ b0,
    const float* __restrict__ g0, const float* __restrict__ be0,
    unsigned short* __restrict__ x_bfi)
{
    int gidx = blockIdx.x * 4 + (threadIdx.x >> 6);  // 0..BB*FCAP-1
    int lane = threadIdx.x & 63;
    int b = gidx / FCAP, i = gidx - b * FCAP;
    int nc = min(cnt[b], FCAP);
    if (i >= nc) return;
    unsigned ent = (unsigned)fixlist[b * FCAP + i];
    int v = (int)(ent & 0xFFFFu);
    int h0 = bt[b * KK * 3];
    float q = query[b * DD + lane];
    float agg = (v == h0) ? q : 0.0f;
    for (int j = 0; j < nc; ++j) {
        unsigned ej = (unsigned)fixlist[b * FCAP + j];
        if ((int)(ej & 0xFFFFu) == v) {
            unsigned et = ej >> 16;
            if (et != 0xFFFFu)
                agg += q * rel_buf[(b * RR + (int)et) * DD + lane];
        }
    }
    float xr = (v == h0) ? q : 0.0f;
    float acc = b0[lane];
#pragma unroll 8
    for (int k = 0; k < DD; ++k) {
        acc += __shfl(xr, k, 64) * W0[k * DD + lane];
        acc += __shfl(agg, k, 64) * W0[(DD + k) * DD + lane];
    }
    float m = wsum64(acc) * (1.0f / DD);
    float c = acc - m;
    float vv = wsum64(c * c) * (1.0f / DD);
    float res = fmaxf(c * rsqrtf(vv + 1e-5f) * g0[lane] + be0[lane], 0.0f) + xr;
    x_bfi[((size_t)v * BB + b) * DD + lane] = f2bf_rne(res);
}

// ==================== fused gather + MFMA dense, layers 2..3 =================
#define XLOAD(p) (*(const ushort4*)&xin_bfi[((size_t)((p) & 0xFFFF) * BB + b) * DD + d0])
#define RLOAD(p) (*(const float4*)&rb[(size_t)((p) >> 16) * DD])

__global__ __launch_bounds__(256) void gather_dense(
    const int* __restrict__ rowptr, const int* __restrict__ pack,
    const int* __restrict__ bt,
    const unsigned short* __restrict__ xin_bfi,
    const float* __restrict__ rel_buf, const float* __restrict__ query,
    const unsigned short* __restrict__ wfrag,
    const float* __restrict__ bias, const float* __restrict__ g,
    const float* __restrict__ beta,
    unsigned short* __restrict__ xout_bfi)
{
    __shared__ unsigned short aggL[4 * 16 * DD];  // 8 KB
    const int wid = (int)(threadIdx.x >> 6);
    const int lane = threadIdx.x & 63;
    const int v0 = blockIdx.x * 16 + wid * 4;
    const int b = lane >> 4;
    const int d0 = (lane & 15) * 4;
    const float* rb = rel_buf + (size_t)b * RR * DD + d0;
    const int h0 = bt[b * KK * 3];
    char* wls = (char*)&aggL[wid * 16 * DD];

    // ---- gather phase: 4-vertex interleaved (8 loads in flight) ----
    int rpa = rowptr[v0 + 0], rpb = rowptr[v0 + 1], rpc = rowptr[v0 + 2];
    int rpd = rowptr[v0 + 3], rpe = rowptr[v0 + 4];
    int len0 = rpb - rpa, len1 = rpc - rpb, len2 = rpd - rpc, len3 = rpe - rpd;
    int maxlen = max(max(len0, len1), max(len2, len3));
    f32x4 ac[4] = {f32x4{0,0,0,0}, f32x4{0,0,0,0}, f32x4{0,0,0,0}, f32x4{0,0,0,0}};
    for (int j = 0; j < maxlen; ++j) {
        ushort4 xv0, xv1, xv2, xv3;
        float4 r0, r1, r2, r3;
        if (j < len0) { int p = pack[rpa + j]; xv0 = XLOAD(p); r0 = RLOAD(p); }
        if (j < len1) { int p = pack[rpb + j]; xv1 = XLOAD(p); r1 = RLOAD(p); }
        if (j < len2) { int p = pack[rpc + j]; xv2 = XLOAD(p); r2 = RLOAD(p); }
        if (j < len3) { int p = pack[rpd + j]; xv3 = XLOAD(p); r3 = RLOAD(p); }
        if (j < len0) { ac[0][0] += bf2f(xv0.x) * r0.x; ac[0][1] += bf2f(xv0.y) * r0.y;
                        ac[0][2] += bf2f(xv0.z) * r0.z; ac[0][3] += bf2f(xv0.w) * r0.w; }
        if (j < len1) { ac[1][0] += bf2f(xv1.x) * r1.x; ac[1][1] += bf2f(xv1.y) * r1.y;
                        ac[1][2] += bf2f(xv1.z) * r1.z; ac[1][3] += bf2f(xv1.w) * r1.w; }
        if (j < len2) { ac[2][0] += bf2f(xv2.x) * r2.x; ac[2][1] += bf2f(xv2.y) * r2.y;
                        ac[2][2] += bf2f(xv2.z) * r2.z; ac[2][3] += bf2f(xv2.w) * r2.w; }
        if (j < len3) { ac[3][0] += bf2f(xv3.x) * r3.x; ac[3][1] += bf2f(xv3.y) * r3.y;
                        ac[3][2] += bf2f(xv3.z) * r3.z; ac[3][3] += bf2f(xv3.w) * r3.w; }
    }
#pragma unroll
    for (int vv = 0; vv < 4; ++vv) {
        f32x4 a = ac[vv];
        if (v0 + vv == h0) {
            float4 q = *(const float4*)&query[b * DD + d0];
            a[0] += q.x; a[1] += q.y; a[2] += q.z; a[3] += q.w;
        }
        ushort4 outv;
        outv.x = f2bf_rne(a[0]); outv.y = f2bf_rne(a[1]);
        outv.z = f2bf_rne(a[2]); outv.w = f2bf_rne(a[3]);
        int row = vv * 4 + b;
        int off = (row * 128 + d0 * 2) ^ ((row & 7) << 4);
        *(ushort4*)(wls + off) = outv;
    }
    __syncthreads();

    // ---- dense phase ----
    s16x8 bfr[4][4];
#pragma unroll
    for (int t = 0; t < 4; ++t)
#pragma unroll
        for (int s = 0; s < 4; ++s)
            bfr[s][t] = *(const s16x8*)&wfrag[((size_t)(t * 4 + s) * 64 + lane) * 8];

    f32x4 acc[4] = {f32x4{0,0,0,0}, f32x4{0,0,0,0}, f32x4{0,0,0,0}, f32x4{0,0,0,0}};
    const int base = v0 * 4;
    const int lrow = lane & 15;
    const size_t arow = (size_t)(base + lrow) * DD;
    const int koff = (lane >> 4) * 8;
#pragma unroll
    for (int s = 0; s < 4; ++s) {
        s16x8 a;
        if (s < 2) {
            a = *(const s16x8*)(xin_bfi + arow + s * 32 + koff);
        } else {
            int off = (lrow * 128 + ((s - 2) * 32 + koff) * 2) ^ ((lrow & 7) << 4);
            a = *(const s16x8*)(wls + off);
        }
#pragma unroll
        for (int t = 0; t < 4; ++t)
            acc[t] = __builtin_amdgcn_mfma_f32_16x16x32_bf16(a, bfr[s][t], acc[t], 0, 0, 0);
    }

    float bia[4], gt[4], bet[4];
#pragma unroll
    for (int t = 0; t < 4; ++t) {
        int col = (lane & 15) + 16 * t;
        bia[t] = bias[col]; gt[t] = g[col]; bet[t] = beta[col];
    }
#pragma unroll
    for (int r = 0; r < 4; ++r) {
        float v0f = acc[0][r] + bia[0];
        float v1f = acc[1][r] + bia[1];
        float v2f = acc[2][r] + bia[2];
        float v3f = acc[3][r] + bia[3];
        float sum = v0f + v1f + v2f + v3f;
#pragma unroll
        for (int off = 1; off < 16; off <<= 1) sum += __shfl_xor(sum, off, 64);
        float m = sum * (1.0f / DD);
        float c0 = v0f - m, c1 = v1f - m, c2 = v2f - m, c3 = v3f - m;
        float q = c0 * c0 + c1 * c1 + c2 * c2 + c3 * c3;
#pragma unroll
        for (int off = 1; off < 16; off <<= 1) q += __shfl_xor(q, off, 64);
        float inv = rsqrtf(q * (1.0f / DD) + 1e-5f);
        int rf = base + (lane >> 4) * 4 + r;
        size_t irow = (size_t)rf * DD;
        float cs[4] = {c0, c1, c2, c3};
#pragma unroll
        for (int t = 0; t < 4; ++t) {
            int col = (lane & 15) + 16 * t;
            float xo = bf2f(xin_bfi[irow + col]);
            float o = cs[t] * inv * gt[t] + bet[t];
            float res = fmaxf(o, 0.0f) + xo;
            xout_bfi[irow + col] = f2bf_rne(res);
        }
    }
}

// ==================== layer-1: constant fast path ============================
// x after layer 0 == dvec everywhere except union-fixset (bitmap). Non-fixed
// edges accumulate rel only; multiply once by dvec. No x loads in steady state.
__global__ __launch_bounds__(256) void gather_dense_l1(
    const int* __restrict__ rowptr, const int* __restrict__ pack,
    const int* __restrict__ bt, const unsigned* __restrict__ fixbit,
    const unsigned short* __restrict__ xin_bfi,
    const float* __restrict__ rel_buf, const float* __restrict__ query,
    const unsigned short* __restrict__ wfrag,
    const float* __restrict__ bias, const float* __restrict__ g,
    const float* __restrict__ beta,
    const float* __restrict__ b0, const float* __restrict__ g0,
    const float* __restrict__ be0,
    unsigned short* __restrict__ xout_bfi)
{
    __shared__ unsigned short aggL[4 * 16 * DD];  // 8 KB
    __shared__ unsigned bm[NFB];                  // 6.27 KB
    __shared__ float dv_f[DD];
    __shared__ unsigned short dv_h[DD];
    const int wid = (int)(threadIdx.x >> 6);
    const int lane = threadIdx.x & 63;
    for (int i = threadIdx.x; i < NFB; i += 256) bm[i] = fixbit[i];
    if (wid == 0) {
        float bv = b0[lane];
        float m = wsum64(bv) * (1.0f / DD);
        float c = bv - m;
        float v = wsum64(c * c) * (1.0f / DD);
        float d = fmaxf(c * rsqrtf(v + 1e-5f) * g0[lane] + be0[lane], 0.0f);
        unsigned short dh = f2bf_rne(d);
        dv_h[lane] = dh;
        dv_f[lane] = bf2f(dh);   // match bf16-rounded state exactly
    }
    __syncthreads();

    const int v0 = blockIdx.x * 16 + wid * 4;
    const int b = lane >> 4;
    const int d0 = (lane & 15) * 4;
    const float* rb = rel_buf + (size_t)b * RR * DD + d0;
    const int h0 = bt[b * KK * 3];
    char* wls = (char*)&aggL[wid * 16 * DD];
    const float4 dv4 = *(const float4*)&dv_f[d0];

    // ---- gather: rel-sum for non-fixed srcs, full product for fixed ----
    int rpa = rowptr[v0 + 0], rpb = rowptr[v0 + 1], rpc = rowptr[v0 + 2];
    int rpd = rowptr[v0 + 3], rpe = rowptr[v0 + 4];
    int len0 = rpb - rpa, len1 = rpc - rpb, len2 = rpd - rpc, len3 = rpe - rpd;
    int maxlen = max(max(len0, len1), max(len2, len3));
    f32x4 ac[4] = {f32x4{0,0,0,0}, f32x4{0,0,0,0}, f32x4{0,0,0,0}, f32x4{0,0,0,0}};
    f32x4 ar[4] = {f32x4{0,0,0,0}, f32x4{0,0,0,0}, f32x4{0,0,0,0}, f32x4{0,0,0,0}};
    for (int j = 0; j < maxlen; ++j) {
        int p0, p1, p2, p3;
        bool f0 = false, f1 = false, f2 = false, f3 = false;
        ushort4 xv0, xv1, xv2, xv3;
        float4 r0, r1, r2, r3;
        if (j < len0) { p0 = pack[rpa + j]; int s = p0 & 0xFFFF;
                        f0 = (bm[s >> 5] >> (s & 31)) & 1; r0 = RLOAD(p0);
                        if (f0) xv0 = XLOAD(p0); }
        if (j < len1) { p1 = pack[rpb + j]; int s = p1 & 0xFFFF;
                        f1 = (bm[s >> 5] >> (s & 31)) & 1; r1 = RLOAD(p1);
                        if (f1) xv1 = XLOAD(p1); }
        if (j < len2) { p2 = pack[rpc + j]; int s = p2 & 0xFFFF;
                        f2 = (bm[s >> 5] >> (s & 31)) & 1; r2 = RLOAD(p2);
                        if (f2) xv2 = XLOAD(p2); }
        if (j < len3) { p3 = pack[rpd + j]; int s = p3 & 0xFFFF;
                        f3 = (bm[s >> 5] >> (s & 31)) & 1; r3 = RLOAD(p3);
                        if (f3) xv3 = XLOAD(p3); }
        if (j < len0) { if (f0) { ac[0][0] += bf2f(xv0.x) * r0.x; ac[0][1] += bf2f(xv0.y) * r0.y;
                                  ac[0][2] += bf2f(xv0.z) * r0.z; ac[0][3] += bf2f(xv0.w) * r0.w; }
                        else    { ar[0][0] += r0.x; ar[0][1] += r0.y; ar[0][2] += r0.z; ar[0][3] += r0.w; } }
        if (j < len1) { if (f1) { ac[1][0] += bf2f(xv1.x) * r1.x; ac[1][1] += bf2f(xv1.y) * r1.y;
                                  ac[1][2] += bf2f(xv1.z) * r1.z; ac[1][3] += bf2f(xv1.w) * r1.w; }
                        else    { ar[1][0] += r1.x; ar[1][1] += r1.y; ar[1][2] += r1.z; ar[1][3] += r1.w; } }
        if (j < len2) { if (f2) { ac[2][0] += bf2f(xv2.x) * r2.x; ac[2][1] += bf2f(xv2.y) * r2.y;
                                  ac[2][2] += bf2f(xv2.z) * r2.z; ac[2][3] += bf2f(xv2.w) * r2.w; }
                        else    { ar[2][0] += r2.x; ar[2][1] += r2.y; ar[2][2] += r2.z; ar[2][3] += r2.w; } }
        if (j < len3) { if (f3) { ac[3][0] += bf2f(xv3.x) * r3.x; ac[3][1] += bf2f(xv3.y) * r3.y;
                                  ac[3][2] += bf2f(xv3.z) * r3.z; ac[3][3] += bf2f(xv3.w) * r3.w; }
                        else    { ar[3][0] += r3.x; ar[3][1] += r3.y; ar[3][2] += r3.z; ar[3][3] += r3.w; } }
    }
#pragma unroll
    for (int vv = 0; vv < 4; ++vv) {
        f32x4 a = ac[vv];
        a[0] += dv4.x * ar[vv][0]; a[1] += dv4.y * ar[vv][1];
        a[2] += dv4.z * ar[vv][2]; a[3] += dv4.w * ar[vv][3];
        if (v0 + vv == h0) {
            float4 q = *(const float4*)&query[b * DD + d0];
            a[0] += q.x; a[1] += q.y; a[2] += q.z; a[3] += q.w;
        }
        ushort4 outv;
        outv.x = f2bf_rne(a[0]); outv.y = f2bf_rne(a[1]);
        outv.z = f2bf_rne(a[2]); outv.w = f2bf_rne(a[3]);
        int row = vv * 4 + b;
        int off = (row * 128 + d0 * 2) ^ ((row & 7) << 4);
        *(ushort4*)(wls + off) = outv;
    }
    __syncthreads();

    // ---- dense phase: x rows are dvec unless fixed ----
    s16x8 bfr[4][4];
#pragma unroll
    for (int t = 0; t < 4; ++t)
#pragma unroll
        for (int s = 0; s < 4; ++s)
            bfr[s][t] = *(const s16x8*)&wfrag[((size_t)(t * 4 + s) * 64 + lane) * 8];

    f32x4 acc[4] = {f32x4{0,0,0,0}, f32x4{0,0,0,0}, f32x4{0,0,0,0}, f32x4{0,0,0,0}};
    const int base = v0 * 4;
    const int lrow = lane & 15;
    const size_t arow = (size_t)(base + lrow) * DD;
    const int koff = (lane >> 4) * 8;
    const int vownA = (base + lrow) >> 2;
    const bool fxA = (bm[vownA >> 5] >> (vownA & 31)) & 1;
#pragma unroll
    for (int s = 0; s < 4; ++s) {
        s16x8 a;
        if (s < 2) {
            if (fxA) a = *(const s16x8*)(xin_bfi + arow + s * 32 + koff);
            else     a = *(const s16x8*)&dv_h[s * 32 + koff];
        } else {
            int off = (lrow * 128 + ((s - 2) * 32 + koff) * 2) ^ ((lrow & 7) << 4);
            a = *(const s16x8*)(wls + off);
        }
#pragma unroll
        for (int t = 0; t < 4; ++t)
            acc[t] = __builtin_amdgcn_mfma_f32_16x16x32_bf16(a, bfr[s][t], acc[t], 0, 0, 0);
    }

    float bia[4], gt[4], bet[4];
#pragma unroll
    for (int t = 0; t < 4; ++t) {
        int col = (lane & 15) + 16 * t;
        bia[t] = bias[col]; gt[t] = g[col]; bet[t] = beta[col];
    }
#pragma unroll
    for (int r = 0; r < 4; ++r) {
        float v0f = acc[0][r] + bia[0];
        float v1f = acc[1][r] + bia[1];
        float v2f = acc[2][r] + bia[2];
        float v3f = acc[3][r] + bia[3];
        float sum = v0f + v1f + v2f + v3f;
#pragma unroll
        for (int off = 1; off < 16; off <<= 1) sum += __shfl_xor(sum, off, 64);
        float m = sum * (1.0f / DD);
        float c0 = v0f - m, c1 = v1f - m, c2 = v2f - m, c3 = v3f - m;
        float q = c0 * c0 + c1 * c1 + c2 * c2 + c3 * c3;
#pragma unroll
        for (int off = 1; off < 16; off <<= 1) q += __shfl_xor(q, off, 64);
        float inv = rsqrtf(q * (1.0f / DD) + 1e-5f);
        int rf = base + (lane >> 4) * 4 + r;
        int vown = rf >> 2;
        bool fx = (bm[vown >> 5] >> (vown & 31)) & 1;
        size_t irow = (size_t)rf * DD;
        float cs[4] = {c0, c1, c2, c3};
#pragma unroll
        for (int t = 0; t < 4; ++t) {
            int col = (lane & 15) + 16 * t;
            float xo = fx ? bf2f(xin_bfi[irow + col]) : dv_f[col];
            float o = cs[t] * inv * gt[t] + bet[t];
            float res = fmaxf(o, 0.0f) + xo;
            xout_bfi[irow + col] = f2bf_rne(res);
        }
    }
}

// ==================== readout ================================================
__global__ __launch_bounds__(128) void readout(
    const int* __restrict__ bt, const unsigned short* __restrict__ x_bfi,
    const float* __restrict__ query,
    const float* __restrict__ W1, const float* __restrict__ b1,
    const float* __restrict__ W2, const float* __restrict__ b2,
    float* __restrict__ out)
{
    int b = blockIdx.x / KK, k = blockIdx.x - b * KK;
    int t = bt[(b * KK + k) * 3 + 1];
    __shared__ float feat[2 * DD];
    __shared__ float red[2 * DD];
    int j = threadIdx.x;
    if (j < DD) feat[j] = bf2f(x_bfi[((size_t)t * BB + b) * DD + j]);
    else        feat[j] = query[b * DD + (j - DD)];
    __syncthreads();
    float h = b1[j];
#pragma unroll 8
    for (int i = 0; i < 2 * DD; ++i) h += feat[i] * W1[i * 2 * DD + j];
    h = fmaxf(h, 0.0f);
    red[j] = h * W2[j];
    __syncthreads();
    for (int s = 64; s > 0; s >>= 1) {
        if (j < s) red[j] += red[j + s];
        __syncthreads();
    }
    if (j == 0) out[blockIdx.x] = red[0] + b2[0];
}

extern "C" void kernel_launch(void* const* d_in, const int* in_sizes, int n_in,
                              void* d_out, int out_size, void* d_ws, size_t ws_size,
                              hipStream_t stream) {
    const int*   edge_index     = (const int*)d_in[0];
    const int*   edge_type      = (const int*)d_in[1];
    const int*   rel_edge_index = (const int*)d_in[2];
    const int*   rel_edge_type  = (const int*)d_in[3];
    const int*   batch_triples  = (const int*)d_in[4];
    const float* rel_emb        = (const float*)d_in[5];
    const float* rel_W          = (const float*)d_in[6];
    const float* rel_b          = (const float*)d_in[7];
    const float* rel_g          = (const float*)d_in[8];
    const float* rel_beta       = (const float*)d_in[9];
    const float* proj_W1        = (const float*)d_in[10];
    const float* proj_b1        = (const float*)d_in[11];
    const float* proj_W2        = (const float*)d_in[12];
    const float* proj_b2        = (const float*)d_in[13];
    const float* ent_W          = (const float*)d_in[14];
    const float* ent_b          = (const float*)d_in[15];
    const float* ent_g          = (const float*)d_in[16];
    const float* ent_beta       = (const float*)d_in[17];
    const float* mlp_W1         = (const float*)d_in[18];
    const float* mlp_b1         = (const float*)d_in[19];
    const float* mlp_W2         = (const float*)d_in[20];
    const float* mlp_b2         = (const float*)d_in[21];

    float* ws = (float*)d_ws;
    float* xrel0    = ws;                                   // B*R*D
    float* xrel1    = xrel0    + BB * RR * DD;              // B*R*D
    float* rel_buf4 = xrel1    + BB * RR * DD;              // 4*B*R*D
    float* query    = rel_buf4 + 4 * BB * RR * DD;          // B*D
    int*   deg      = (int*)(query + BB * DD);              // N
    unsigned* fixbit = (unsigned*)(deg + NN);               // NFB
    int*   rowptr   = (int*)(fixbit + NFB);                 // N+1
    int*   cursor   = rowptr + NN + 1;                      // N
    int*   pack     = cursor + NN;                          // E
    int*   fixlist  = pack + EE;                            // BB*FCAP
    int*   fixcnt   = fixlist + BB * FCAP;                  // BB
    int*   bsum     = fixcnt + BB;                          // NSB (pad 256)
    int*   boff     = bsum + 256;                           // NSB (pad 256)
    int*   rptrR    = boff + 256;                           // RR+1 (pad 66)
    int*   rpackR   = rptrR + 66;                           // ERE
    uintptr_t wp = (uintptr_t)(rpackR + ERE);
    wp = (wp + 15) & ~(uintptr_t)15;
    unsigned short* wbf    = (unsigned short*)wp;           // 3*16*64*8
    unsigned short* x_bfiA = wbf + 3 * 16 * 64 * 8;         // B*N*D bf16 [v][b][d]
    unsigned short* x_bfiB = x_bfiA + (size_t)BB * NN * DD; // B*N*D bf16 [v][b][d]

    // ---- CSR build + fixlist/bitmap + rel CSR + W fragment pack ----
    hipMemsetAsync(deg, 0, sizeof(int) * (NN + NFB), stream);  // deg + fixbit
    hipMemsetAsync(fixcnt, 0, sizeof(int) * BB, stream);
    edge_scan<<<(EE + 255) / 256, 256, 0, stream>>>(
        edge_index, edge_type, batch_triples, deg, fixlist, fixcnt, fixbit);
    scan_a<<<NSB, 256, 0, stream>>>(deg, bsum);
    setup_small<<<50, 256, 0, stream>>>(
        bsum, boff, rowptr, rel_edge_index, rel_edge_type, rptrR, rpackR,
        ent_W, wbf);
    scan_c<<<NSB, 256, 0, stream>>>(deg, boff, rowptr, cursor);
    csr_fill<<<(EE + 255) / 256, 256, 0, stream>>>(edge_index, edge_type, cursor, pack);

    // ---- relation stage ----
    rel_layer0<<<BB * RR / 4, 256, 0, stream>>>(
        rptrR, rpackR, batch_triples, rel_emb,
        rel_W, rel_b, rel_g, rel_beta, xrel1);
    for (int l = 1; l < LL; ++l) {
        const float* xin = (l & 1) ? xrel1 : xrel0;
        float* xout = (l & 1) ? xrel0 : xrel1;
        rel_layer<<<BB * RR / 4, 256, 0, stream>>>(
            rptrR, rpackR, batch_triples, rel_emb + l * RT * DD,
            rel_W + l * 2 * DD * DD, rel_b + l * DD,
            rel_g + l * DD, rel_beta + l * DD, xin, xout);
    }
    float* rel_repr = xrel0;
    rel_projq<<<4 * BB * RR / 4, 256, 0, stream>>>(
        rel_repr, batch_triples, proj_W1, proj_b1, proj_W2, proj_b2,
        rel_buf4, query);

    // ---- entity stage: layer 0 (seed union-fixset rows, then fix) ----
    l0_seed<<<(BB * FCAP) / 4, 256, 0, stream>>>(
        fixlist, fixcnt, ent_b, ent_g, ent_beta, x_bfiA);
    l0_fix<<<(BB * FCAP) / 4, 256, 0, stream>>>(
        batch_triples, fixlist, fixcnt, query, rel_buf4,
        ent_W, ent_b, ent_g, ent_beta, x_bfiA);

    // ---- entity stage: layer 1 (constant fast path) ----
    gather_dense_l1<<<NN / 16, 256, 0, stream>>>(
        rowptr, pack, batch_triples, fixbit, x_bfiA,
        rel_buf4 + 1 * BB * RR * DD, query,
        wbf + 0 * 16 * 64 * 8,
        ent_b + 1 * DD, ent_g + 1 * DD, ent_beta + 1 * DD,
        ent_b, ent_g, ent_beta, x_bfiB);

    // ---- entity stage: layers 2..3 ----
    unsigned short* bufs[2] = {x_bfiA, x_bfiB};
    for (int l = 2; l < LL; ++l) {
        gather_dense<<<NN / 16, 256, 0, stream>>>(
            rowptr, pack, batch_triples, bufs[(l - 1) & 1],
            rel_buf4 + l * BB * RR * DD, query,
            wbf + (size_t)(l - 1) * 16 * 64 * 8,
            ent_b + l * DD, ent_g + l * DD, ent_beta + l * DD,
            bufs[l & 1]);
    }

    readout<<<BB * KK, 2 * DD, 0, stream>>>(batch_triples, bufs[1], query,
                                            mlp_W1, mlp_b1, mlp_W2, mlp_b2,
                                            (float*)d_out);
}

// Round 16
// 277.949 us; speedup vs baseline: 1.1631x; 1.1631x over previous
//
#include <hip/hip_runtime.h>
#include <hip/hip_bf16.h>

#define BB 4
#define KK 16
#define NN 50000
#define EE 300000
#define RR 64
#define ERE 2048
#define RT 4
#define DD 64
#define LL 4
#define FCAP 256
#define NSB 196   // (NN+255)/256
#define NFB 1568  // bitmap ints, >= (NN+31)/32

typedef short s16x8 __attribute__((ext_vector_type(8)));
typedef float f32x4 __attribute__((ext_vector_type(4)));

__device__ __forceinline__ float wsum64(float v) {
#pragma unroll
    for (int off = 32; off > 0; off >>= 1) v += __shfl_xor(v, off, 64);
    return v;
}

__device__ __forceinline__ unsigned short f2bf_rne(float f) {
    unsigned u = __builtin_bit_cast(unsigned, f);
    return (unsigned short)((u + 0x7FFFu + ((u >> 16) & 1u)) >> 16);
}

__device__ __forceinline__ float bf2f(unsigned short h) {
    unsigned u = ((unsigned)h) << 16;
    return __builtin_bit_cast(float, u);
}

// ==================== fused edge pass: histogram + fixlist + fix bitmap ======
__global__ __launch_bounds__(256) void edge_scan(
    const int* __restrict__ edge_index, const int* __restrict__ edge_type,
    const int* __restrict__ bt, int* __restrict__ deg,
    int* __restrict__ fixlist, int* __restrict__ cnt,
    unsigned* __restrict__ fixbit)
{
    int e = blockIdx.x * 256 + threadIdx.x;
    if (e < BB) {
        int h0 = bt[e * KK * 3];
        int pos = atomicAdd(&cnt[e], 1);
        if (pos < FCAP) fixlist[e * FCAP + pos] = h0 | (int)(0xFFFFu << 16);
        atomicOr(&fixbit[h0 >> 5], 1u << (h0 & 31));
    }
    if (e >= EE) return;
    int s = edge_index[e];
    int d = edge_index[EE + e];
    int t = edge_type[e];
    atomicAdd(&deg[d], 1);
#pragma unroll
    for (int b = 0; b < BB; ++b) {
        int h0 = bt[b * KK * 3];
        if (s == h0) {
            int pos = atomicAdd(&cnt[b], 1);
            if (pos < FCAP) fixlist[b * FCAP + pos] = d | (t << 16);
            atomicOr(&fixbit[d >> 5], 1u << (d & 31));
        }
    }
}

// ==================== scan pipeline ==========================================
__global__ __launch_bounds__(256) void scan_a(
    const int* __restrict__ deg, int* __restrict__ bsum)
{
    int i = blockIdx.x * 256 + threadIdx.x;
    int v = (i < NN) ? deg[i] : 0;
    int s = v;
#pragma unroll
    for (int off = 32; off > 0; off >>= 1) s += __shfl_xor(s, off, 64);
    __shared__ int ls[4];
    if ((threadIdx.x & 63) == 0) ls[threadIdx.x >> 6] = s;
    __syncthreads();
    if (threadIdx.x == 0) bsum[blockIdx.x] = ls[0] + ls[1] + ls[2] + ls[3];
}

__global__ __launch_bounds__(256) void setup_small(
    const int* __restrict__ bsum, int* __restrict__ boff, int* __restrict__ rowptr,
    const int* __restrict__ rel_edge_index, const int* __restrict__ rel_edge_type,
    int* __restrict__ rptr, int* __restrict__ rpack,
    const float* __restrict__ entW, unsigned short* __restrict__ wbf)
{
    int t = threadIdx.x;
    if (blockIdx.x == 0) {
        __shared__ int tmp[256];
        int v = (t < NSB) ? bsum[t] : 0;
        tmp[t] = v;
        __syncthreads();
        for (int off = 1; off < 256; off <<= 1) {
            int u = (t >= off) ? tmp[t - off] : 0;
            __syncthreads();
            tmp[t] += u;
            __syncthreads();
        }
        if (t < NSB) boff[t] = tmp[t] - v;
        if (t == 0) rowptr[NN] = EE;
    } else if (blockIdx.x == 1) {
        __shared__ int hdeg[RR];
        __shared__ int hcur[RR];
        if (t < RR) hdeg[t] = 0;
        __syncthreads();
        for (int e = t; e < ERE; e += 256) atomicAdd(&hdeg[rel_edge_index[ERE + e]], 1);
        __syncthreads();
        if (t == 0) {
            int run = 0;
            for (int r = 0; r < RR; ++r) { hcur[r] = run; rptr[r] = run; run += hdeg[r]; }
            rptr[RR] = run;
        }
        __syncthreads();
        for (int e = t; e < ERE; e += 256) {
            int s = rel_edge_index[e];
            int d = rel_edge_index[ERE + e];
            int ty = rel_edge_type[e];
            int pos = atomicAdd(&hcur[d], 1);
            rpack[pos] = s | (ty << 16);
        }
    } else {
        if (t >= 64) return;
        int blk = blockIdx.x - 2;        // li*16 + tt*4 + s
        int li = blk >> 4;
        int tt = (blk >> 2) & 3, s = blk & 3;
        const float* W = entW + (li + 1) * 2 * DD * DD;
        unsigned short* dst = wbf + ((size_t)blk * 64 + t) * 8;
#pragma unroll
        for (int j = 0; j < 8; ++j) {
            int k = s * 32 + (t >> 4) * 8 + j;
            int n = tt * 16 + (t & 15);
            dst[j] = f2bf_rne(W[k * DD + n]);
        }
    }
}

__global__ __launch_bounds__(256) void scan_c(
    const int* __restrict__ deg, const int* __restrict__ boff,
    int* __restrict__ rowptr, int* __restrict__ cursor)
{
    __shared__ int tmp[256];
    int t = threadIdx.x;
    int i = blockIdx.x * 256 + t;
    int v = (i < NN) ? deg[i] : 0;
    tmp[t] = v;
    __syncthreads();
    for (int off = 1; off < 256; off <<= 1) {
        int u = (t >= off) ? tmp[t - off] : 0;
        __syncthreads();
        tmp[t] += u;
        __syncthreads();
    }
    if (i < NN) {
        int excl = tmp[t] - v + boff[blockIdx.x];
        rowptr[i] = excl;
        cursor[i] = excl;
    }
}

__global__ __launch_bounds__(256) void csr_fill(
    const int* __restrict__ edge_index, const int* __restrict__ edge_type,
    int* __restrict__ cursor, int* __restrict__ pack)
{
    int e = blockIdx.x * 256 + threadIdx.x;
    if (e >= EE) return;
    int s = edge_index[e];
    int d = edge_index[EE + e];
    int t = edge_type[e];
    int pos = atomicAdd(&cursor[d], 1);
    pack[pos] = s | (t << 16);  // src < 2^16, et < 64
}

// ==================== relation stage =========================================
__global__ __launch_bounds__(256) void rel_layer0(
    const int* __restrict__ rptr, const int* __restrict__ rpack,
    const int* __restrict__ bt, const float* __restrict__ emb,
    const float* __restrict__ W, const float* __restrict__ bias,
    const float* __restrict__ g, const float* __restrict__ beta,
    float* __restrict__ xout)
{
    int row = blockIdx.x * 4 + (int)(threadIdx.x >> 6);  // 0..BB*RR-1
    int lane = threadIdx.x & 63;
    int b = row >> 6, r = row & 63;
    int r0 = bt[(b * KK) * 3 + 2];
    int beg = rptr[r], end = rptr[r + 1];
    float av = (r == r0) ? 1.0f : 0.0f;
    for (int j = beg; j < end; ++j) {
        int p = rpack[j];
        if ((p & 0xFFFF) == r0) av += emb[(p >> 16) * DD + lane];
    }
    float xv = (r == r0) ? 1.0f : 0.0f;
    float acc = bias[lane];
#pragma unroll 8
    for (int k = 0; k < DD; ++k) {
        acc += __shfl(xv, k, 64) * W[k * DD + lane];
        acc += __shfl(av, k, 64) * W[(DD + k) * DD + lane];
    }
    float m = wsum64(acc) * (1.0f / DD);
    float c = acc - m;
    float v = wsum64(c * c) * (1.0f / DD);
    float o = c * rsqrtf(v + 1e-5f) * g[lane] + beta[lane];
    xout[row * DD + lane] = fmaxf(o, 0.0f) + xv;
}

__global__ __launch_bounds__(256) void rel_layer(
    const int* __restrict__ rptr, const int* __restrict__ rpack,
    const int* __restrict__ bt, const float* __restrict__ emb,
    const float* __restrict__ W, const float* __restrict__ bias,
    const float* __restrict__ g, const float* __restrict__ beta,
    const float* __restrict__ xin, float* __restrict__ xout)
{
    int row = blockIdx.x * 4 + (int)(threadIdx.x >> 6);  // 0..BB*RR-1
    int lane = threadIdx.x & 63;
    int b = row >> 6, r = row & 63;
    int r0 = bt[(b * KK) * 3 + 2];
    int beg = rptr[r], end = rptr[r + 1];
    const float* xb = xin + b * RR * DD;
    float av = (r == r0) ? 1.0f : 0.0f;
    for (int j = beg; j < end; ++j) {
        int p = rpack[j];
        av += xb[(p & 0xFFFF) * DD + lane] * emb[(p >> 16) * DD + lane];
    }
    float xv = xin[row * DD + lane];
    float acc = bias[lane];
#pragma unroll 8
    for (int k = 0; k < DD; ++k) {
        acc += __shfl(xv, k, 64) * W[k * DD + lane];
        acc += __shfl(av, k, 64) * W[(DD + k) * DD + lane];
    }
    float m = wsum64(acc) * (1.0f / DD);
    float c = acc - m;
    float v = wsum64(c * c) * (1.0f / DD);
    float o = c * rsqrtf(v + 1e-5f) * g[lane] + beta[lane];
    xout[row * DD + lane] = fmaxf(o, 0.0f) + xv;
}

// all-4-layer projection + query extraction (block 0)
__global__ __launch_bounds__(256) void rel_projq(
    const float* __restrict__ rel_repr, const int* __restrict__ bt,
    const float* __restrict__ W1, const float* __restrict__ b1,
    const float* __restrict__ W2, const float* __restrict__ b2,
    float* __restrict__ rel_buf4, float* __restrict__ query)
{
    int grow = blockIdx.x * 4 + (int)(threadIdx.x >> 6);  // 0..4*B*R-1
    int lane = threadIdx.x & 63;
    int l = grow / (BB * RR);
    int row = grow - l * (BB * RR);
    const float* xr = &rel_repr[row * DD];
    const float* w1 = W1 + l * DD * DD;
    const float* w2 = W2 + l * DD * DD;
    float h = b1[l * DD + lane];
#pragma unroll 8
    for (int k = 0; k < DD; ++k) h += xr[k] * w1[k * DD + lane];
    h = fmaxf(h, 0.0f);
    float o = b2[l * DD + lane];
#pragma unroll 8
    for (int k = 0; k < DD; ++k) o += __shfl(h, k, 64) * w2[k * DD + lane];
    rel_buf4[grow * DD + lane] = o;
    if (blockIdx.x == 0) {
        int i = threadIdx.x;  // 0..255 = B*D
        int b = i / DD, d = i - b * DD;
        int r0 = bt[(b * KK) * 3 + 2];
        query[b * DD + d] = rel_repr[(b * RR + r0) * DD + d];
    }
}

// ==================== entity stage ===========================================
// seed the union-fixset rows of x_bfiA with dvec (bf16 of LN(bias) default)
__global__ __launch_bounds__(256) void l0_seed(
    const int* __restrict__ fixlist, const int* __restrict__ cnt,
    const float* __restrict__ b0, const float* __restrict__ g0,
    const float* __restrict__ be0, unsigned short* __restrict__ x_bfi)
{
    int gidx = blockIdx.x * 4 + (int)(threadIdx.x >> 6);  // (bl, i)
    int lane = threadIdx.x & 63;
    float bv = b0[lane];
    float m = wsum64(bv) * (1.0f / DD);
    float c = bv - m;
    float v = wsum64(c * c) * (1.0f / DD);
    float dvec = fmaxf(c * rsqrtf(v + 1e-5f) * g0[lane] + be0[lane], 0.0f);
    int bl = gidx / FCAP, i = gidx - bl * FCAP;
    int nc = min(cnt[bl], FCAP);
    if (i >= nc) return;
    int vx = fixlist[bl * FCAP + i] & 0xFFFF;
    int b = lane >> 4, d0 = (lane & 15) * 4;
    ushort4 o;
    o.x = f2bf_rne(__shfl(dvec, d0 + 0, 64));
    o.y = f2bf_rne(__shfl(dvec, d0 + 1, 64));
    o.z = f2bf_rne(__shfl(dvec, d0 + 2, 64));
    o.w = f2bf_rne(__shfl(dvec, d0 + 3, 64));
    *(ushort4*)&x_bfi[((size_t)vx * BB + b) * DD + d0] = o;
}

__global__ __launch_bounds__(256) void l0_fix(
    const int* __restrict__ bt, const int* __restrict__ fixlist,
    const int* __restrict__ cnt, const float* __restrict__ query,
    const float* __restrict__ rel_buf,
    const float* __restrict__ W0, const float* __restrict__ b0,
    const float* __restrict__ g0, const float* __restrict__ be0,
    unsigned short* __restrict__ x_bfi)
{
    int gidx = blockIdx.x * 4 + (threadIdx.x >> 6);  // 0..BB*FCAP-1
    int lane = threadIdx.x & 63;
    int b = gidx / FCAP, i = gidx - b * FCAP;
    int nc = min(cnt[b], FCAP);
    if (i >= nc) return;
    unsigned ent = (unsigned)fixlist[b * FCAP + i];
    int v = (int)(ent & 0xFFFFu);
    int h0 = bt[b * KK * 3];
    float q = query[b * DD + lane];
    float agg = (v == h0) ? q : 0.0f;
    for (int j = 0; j < nc; ++j) {
        unsigned ej = (unsigned)fixlist[b * FCAP + j];
        if ((int)(ej & 0xFFFFu) == v) {
            unsigned et = ej >> 16;
            if (et != 0xFFFFu)
                agg += q * rel_buf[(b * RR + (int)et) * DD + lane];
        }
    }
    float xr = (v == h0) ? q : 0.0f;
    float acc = b0[lane];
#pragma unroll 8
    for (int k = 0; k < DD; ++k) {
        acc += __shfl(xr, k, 64) * W0[k * DD + lane];
        acc += __shfl(agg, k, 64) * W0[(DD + k) * DD + lane];
    }
    float m = wsum64(acc) * (1.0f / DD);
    float c = acc - m;
    float vv = wsum64(c * c) * (1.0f / DD);
    float res = fmaxf(c * rsqrtf(vv + 1e-5f) * g0[lane] + be0[lane], 0.0f) + xr;
    x_bfi[((size_t)v * BB + b) * DD + lane] = f2bf_rne(res);
}

// ==================== fused gather + MFMA dense, layers 2..3 =================
#define XLOAD(p) (*(const ushort4*)&xin_bfi[((size_t)((p) & 0xFFFF) * BB + b) * DD + d0])
#define RLOAD(p) (*(const float4*)&rb[(size_t)((p) >> 16) * DD])

__global__ __launch_bounds__(256) void gather_dense(
    const int* __restrict__ rowptr, const int* __restrict__ pack,
    const int* __restrict__ bt,
    const unsigned short* __restrict__ xin_bfi,
    const float* __restrict__ rel_buf, const float* __restrict__ query,
    const unsigned short* __restrict__ wfrag,
    const float* __restrict__ bias, const float* __restrict__ g,
    const float* __restrict__ beta,
    unsigned short* __restrict__ xout_bfi)
{
    __shared__ unsigned short aggL[4 * 16 * DD];  // 8 KB
    const int wid = (int)(threadIdx.x >> 6);
    const int lane = threadIdx.x & 63;
    const int v0 = blockIdx.x * 16 + wid * 4;
    const int b = lane >> 4;
    const int d0 = (lane & 15) * 4;
    const float* rb = rel_buf + (size_t)b * RR * DD + d0;
    const int h0 = bt[b * KK * 3];
    char* wls = (char*)&aggL[wid * 16 * DD];

    // ---- gather phase: sequential per-vertex, 2-way unrolled ----
    for (int vv = 0; vv < 4; ++vv) {
        int v = v0 + vv;
        int beg = rowptr[v], end = rowptr[v + 1];
        f32x4 acc = {0.0f, 0.0f, 0.0f, 0.0f};
        int j = beg;
        for (; j + 1 < end; j += 2) {
            int p0 = pack[j], p1 = pack[j + 1];
            ushort4 xv0 = XLOAD(p0);
            ushort4 xv1 = XLOAD(p1);
            float4 r0 = RLOAD(p0);
            float4 r1 = RLOAD(p1);
            acc[0] += bf2f(xv0.x) * r0.x + bf2f(xv1.x) * r1.x;
            acc[1] += bf2f(xv0.y) * r0.y + bf2f(xv1.y) * r1.y;
            acc[2] += bf2f(xv0.z) * r0.z + bf2f(xv1.z) * r1.z;
            acc[3] += bf2f(xv0.w) * r0.w + bf2f(xv1.w) * r1.w;
        }
        if (j < end) {
            int p0 = pack[j];
            ushort4 xv0 = XLOAD(p0);
            float4 r0 = RLOAD(p0);
            acc[0] += bf2f(xv0.x) * r0.x;
            acc[1] += bf2f(xv0.y) * r0.y;
            acc[2] += bf2f(xv0.z) * r0.z;
            acc[3] += bf2f(xv0.w) * r0.w;
        }
        if (v == h0) {
            float4 q = *(const float4*)&query[b * DD + d0];
            acc[0] += q.x; acc[1] += q.y; acc[2] += q.z; acc[3] += q.w;
        }
        ushort4 outv;
        outv.x = f2bf_rne(acc[0]); outv.y = f2bf_rne(acc[1]);
        outv.z = f2bf_rne(acc[2]); outv.w = f2bf_rne(acc[3]);
        int row = vv * 4 + b;
        int off = (row * 128 + d0 * 2) ^ ((row & 7) << 4);
        *(ushort4*)(wls + off) = outv;
    }
    __syncthreads();

    // ---- dense phase ----
    s16x8 bfr[4][4];
#pragma unroll
    for (int t = 0; t < 4; ++t)
#pragma unroll
        for (int s = 0; s < 4; ++s)
            bfr[s][t] = *(const s16x8*)&wfrag[((size_t)(t * 4 + s) * 64 + lane) * 8];

    f32x4 acc[4] = {f32x4{0,0,0,0}, f32x4{0,0,0,0}, f32x4{0,0,0,0}, f32x4{0,0,0,0}};
    const int base = v0 * 4;
    const int lrow = lane & 15;
    const size_t arow = (size_t)(base + lrow) * DD;
    const int koff = (lane >> 4) * 8;
#pragma unroll
    for (int s = 0; s < 4; ++s) {
        s16x8 a;
        if (s < 2) {
            a = *(const s16x8*)(xin_bfi + arow + s * 32 + koff);
        } else {
            int off = (lrow * 128 + ((s - 2) * 32 + koff) * 2) ^ ((lrow & 7) << 4);
            a = *(const s16x8*)(wls + off);
        }
#pragma unroll
        for (int t = 0; t < 4; ++t)
            acc[t] = __builtin_amdgcn_mfma_f32_16x16x32_bf16(a, bfr[s][t], acc[t], 0, 0, 0);
    }

    float bia[4], gt[4], bet[4];
#pragma unroll
    for (int t = 0; t < 4; ++t) {
        int col = (lane & 15) + 16 * t;
        bia[t] = bias[col]; gt[t] = g[col]; bet[t] = beta[col];
    }
#pragma unroll
    for (int r = 0; r < 4; ++r) {
        float v0f = acc[0][r] + bia[0];
        float v1f = acc[1][r] + bia[1];
        float v2f = acc[2][r] + bia[2];
        float v3f = acc[3][r] + bia[3];
        float sum = v0f + v1f + v2f + v3f;
#pragma unroll
        for (int off = 1; off < 16; off <<= 1) sum += __shfl_xor(sum, off, 64);
        float m = sum * (1.0f / DD);
        float c0 = v0f - m, c1 = v1f - m, c2 = v2f - m, c3 = v3f - m;
        float q = c0 * c0 + c1 * c1 + c2 * c2 + c3 * c3;
#pragma unroll
        for (int off = 1; off < 16; off <<= 1) q += __shfl_xor(q, off, 64);
        float inv = rsqrtf(q * (1.0f / DD) + 1e-5f);
        int rf = base + (lane >> 4) * 4 + r;
        size_t irow = (size_t)rf * DD;
        float cs[4] = {c0, c1, c2, c3};
#pragma unroll
        for (int t = 0; t < 4; ++t) {
            int col = (lane & 15) + 16 * t;
            float xo = bf2f(xin_bfi[irow + col]);
            float o = cs[t] * inv * gt[t] + bet[t];
            float res = fmaxf(o, 0.0f) + xo;
            xout_bfi[irow + col] = f2bf_rne(res);
        }
    }
}

// ==================== layer-1: constant fast path ============================
// x after layer 0 == dvec everywhere except union-fixset (bitmap). Non-fixed
// edges accumulate rel only; multiply once by dvec. Sequential gather loop.
__global__ __launch_bounds__(256) void gather_dense_l1(
    const int* __restrict__ rowptr, const int* __restrict__ pack,
    const int* __restrict__ bt, const unsigned* __restrict__ fixbit,
    const unsigned short* __restrict__ xin_bfi,
    const float* __restrict__ rel_buf, const float* __restrict__ query,
    const unsigned short* __restrict__ wfrag,
    const float* __restrict__ bias, const float* __restrict__ g,
    const float* __restrict__ beta,
    const float* __restrict__ b0, const float* __restrict__ g0,
    const float* __restrict__ be0,
    unsigned short* __restrict__ xout_bfi)
{
    __shared__ unsigned short aggL[4 * 16 * DD];  // 8 KB
    __shared__ unsigned bm[NFB];                  // 6.27 KB
    __shared__ float dv_f[DD];
    __shared__ unsigned short dv_h[DD];
    const int wid = (int)(threadIdx.x >> 6);
    const int lane = threadIdx.x & 63;
    for (int i = threadIdx.x; i < NFB; i += 256) bm[i] = fixbit[i];
    if (wid == 0) {
        float bv = b0[lane];
        float m = wsum64(bv) * (1.0f / DD);
        float c = bv - m;
        float v = wsum64(c * c) * (1.0f / DD);
        float d = fmaxf(c * rsqrtf(v + 1e-5f) * g0[lane] + be0[lane], 0.0f);
        unsigned short dh = f2bf_rne(d);
        dv_h[lane] = dh;
        dv_f[lane] = bf2f(dh);   // match bf16-rounded state exactly
    }
    __syncthreads();

    const int v0 = blockIdx.x * 16 + wid * 4;
    const int b = lane >> 4;
    const int d0 = (lane & 15) * 4;
    const float* rb = rel_buf + (size_t)b * RR * DD + d0;
    const int h0 = bt[b * KK * 3];
    char* wls = (char*)&aggL[wid * 16 * DD];
    const float4 dv4 = *(const float4*)&dv_f[d0];

    // ---- gather: rel-sum for non-fixed srcs, full product for fixed ----
    for (int vv = 0; vv < 4; ++vv) {
        int v = v0 + vv;
        int beg = rowptr[v], end = rowptr[v + 1];
        f32x4 ac = {0.0f, 0.0f, 0.0f, 0.0f};
        f32x4 ar = {0.0f, 0.0f, 0.0f, 0.0f};
        int j = beg;
        for (; j + 1 < end; j += 2) {
            int p0 = pack[j], p1 = pack[j + 1];
            int s0 = p0 & 0xFFFF, s1 = p1 & 0xFFFF;
            bool f0 = (bm[s0 >> 5] >> (s0 & 31)) & 1;
            bool f1 = (bm[s1 >> 5] >> (s1 & 31)) & 1;
            float4 r0 = RLOAD(p0);
            float4 r1 = RLOAD(p1);
            if (f0) {
                ushort4 xv = XLOAD(p0);
                ac[0] += bf2f(xv.x) * r0.x; ac[1] += bf2f(xv.y) * r0.y;
                ac[2] += bf2f(xv.z) * r0.z; ac[3] += bf2f(xv.w) * r0.w;
            } else {
                ar[0] += r0.x; ar[1] += r0.y; ar[2] += r0.z; ar[3] += r0.w;
            }
            if (f1) {
                ushort4 xv = XLOAD(p1);
                ac[0] += bf2f(xv.x) * r1.x; ac[1] += bf2f(xv.y) * r1.y;
                ac[2] += bf2f(xv.z) * r1.z; ac[3] += bf2f(xv.w) * r1.w;
            } else {
                ar[0] += r1.x; ar[1] += r1.y; ar[2] += r1.z; ar[3] += r1.w;
            }
        }
        if (j < end) {
            int p0 = pack[j];
            int s0 = p0 & 0xFFFF;
            bool f0 = (bm[s0 >> 5] >> (s0 & 31)) & 1;
            float4 r0 = RLOAD(p0);
            if (f0) {
                ushort4 xv = XLOAD(p0);
                ac[0] += bf2f(xv.x) * r0.x; ac[1] += bf2f(xv.y) * r0.y;
                ac[2] += bf2f(xv.z) * r0.z; ac[3] += bf2f(xv.w) * r0.w;
            } else {
                ar[0] += r0.x; ar[1] += r0.y; ar[2] += r0.z; ar[3] += r0.w;
            }
        }
        f32x4 a = ac;
        a[0] += dv4.x * ar[0]; a[1] += dv4.y * ar[1];
        a[2] += dv4.z * ar[2]; a[3] += dv4.w * ar[3];
        if (v == h0) {
            float4 q = *(const float4*)&query[b * DD + d0];
            a[0] += q.x; a[1] += q.y; a[2] += q.z; a[3] += q.w;
        }
        ushort4 outv;
        outv.x = f2bf_rne(a[0]); outv.y = f2bf_rne(a[1]);
        outv.z = f2bf_rne(a[2]); outv.w = f2bf_rne(a[3]);
        int row = vv * 4 + b;
        int off = (row * 128 + d0 * 2) ^ ((row & 7) << 4);
        *(ushort4*)(wls + off) = outv;
    }
    __syncthreads();

    // ---- dense phase: x rows are dvec unless fixed ----
    s16x8 bfr[4][4];
#pragma unroll
    for (int t = 0; t < 4; ++t)
#pragma unroll
        for (int s = 0; s < 4; ++s)
            bfr[s][t] = *(const s16x8*)&wfrag[((size_t)(t * 4 + s) * 64 + lane) * 8];

    f32x4 acc[4] = {f32x4{0,0,0,0}, f32x4{0,0,0,0}, f32x4{0,0,0,0}, f32x4{0,0,0,0}};
    const int base = v0 * 4;
    const int lrow = lane & 15;
    const size_t arow = (size_t)(base + lrow) * DD;
    const int koff = (lane >> 4) * 8;
    const int vownA = (base + lrow) >> 2;
    const bool fxA = (bm[vownA >> 5] >> (vownA & 31)) & 1;
#pragma unroll
    for (int s = 0; s < 4; ++s) {
        s16x8 a;
        if (s < 2) {
            if (fxA) a = *(const s16x8*)(xin_bfi + arow + s * 32 + koff);
            else     a = *(const s16x8*)&dv_h[s * 32 + koff];
        } else {
            int off = (lrow * 128 + ((s - 2) * 32 + koff) * 2) ^ ((lrow & 7) << 4);
            a = *(const s16x8*)(wls + off);
        }
#pragma unroll
        for (int t = 0; t < 4; ++t)
            acc[t] = __builtin_amdgcn_mfma_f32_16x16x32_bf16(a, bfr[s][t], acc[t], 0, 0, 0);
    }

    float bia[4], gt[4], bet[4];
#pragma unroll
    for (int t = 0; t < 4; ++t) {
        int col = (lane & 15) + 16 * t;
        bia[t] = bias[col]; gt[t] = g[col]; bet[t] = beta[col];
    }
#pragma unroll
    for (int r = 0; r < 4; ++r) {
        float v0f = acc[0][r] + bia[0];
        float v1f = acc[1][r] + bia[1];
        float v2f = acc[2][r] + bia[2];
        float v3f = acc[3][r] + bia[3];
        float sum = v0f + v1f + v2f + v3f;
#pragma unroll
        for (int off = 1; off < 16; off <<= 1) sum += __shfl_xor(sum, off, 64);
        float m = sum * (1.0f / DD);
        float c0 = v0f - m, c1 = v1f - m, c2 = v2f - m, c3 = v3f - m;
        float q = c0 * c0 + c1 * c1 + c2 * c2 + c3 * c3;
#pragma unroll
        for (int off = 1; off < 16; off <<= 1) q += __shfl_xor(q, off, 64);
        float inv = rsqrtf(q * (1.0f / DD) + 1e-5f);
        int rf = base + (lane >> 4) * 4 + r;
        int vown = rf >> 2;
        bool fx = (bm[vown >> 5] >> (vown & 31)) & 1;
        size_t irow = (size_t)rf * DD;
        float cs[4] = {c0, c1, c2, c3};
#pragma unroll
        for (int t = 0; t < 4; ++t) {
            int col = (lane & 15) + 16 * t;
            float xo = fx ? bf2f(xin_bfi[irow + col]) : dv_f[col];
            float o = cs[t] * inv * gt[t] + bet[t];
            float res = fmaxf(o, 0.0f) + xo;
            xout_bfi[irow + col] = f2bf_rne(res);
        }
    }
}

// ==================== readout ================================================
__global__ __launch_bounds__(128) void readout(
    const int* __restrict__ bt, const unsigned short* __restrict__ x_bfi,
    const float* __restrict__ query,
    const float* __restrict__ W1, const float* __restrict__ b1,
    const float* __restrict__ W2, const float* __restrict__ b2,
    float* __restrict__ out)
{
    int b = blockIdx.x / KK, k = blockIdx.x - b * KK;
    int t = bt[(b * KK + k) * 3 + 1];
    __shared__ float feat[2 * DD];
    __shared__ float red[2 * DD];
    int j = threadIdx.x;
    if (j < DD) feat[j] = bf2f(x_bfi[((size_t)t * BB + b) * DD + j]);
    else        feat[j] = query[b * DD + (j - DD)];
    __syncthreads();
    float h = b1[j];
#pragma unroll 8
    for (int i = 0; i < 2 * DD; ++i) h += feat[i] * W1[i * 2 * DD + j];
    h = fmaxf(h, 0.0f);
    red[j] = h * W2[j];
    __syncthreads();
    for (int s = 64; s > 0; s >>= 1) {
        if (j < s) red[j] += red[j + s];
        __syncthreads();
    }
    if (j == 0) out[blockIdx.x] = red[0] + b2[0];
}

extern "C" void kernel_launch(void* const* d_in, const int* in_sizes, int n_in,
                              void* d_out, int out_size, void* d_ws, size_t ws_size,
                              hipStream_t stream) {
    const int*   edge_index     = (const int*)d_in[0];
    const int*   edge_type      = (const int*)d_in[1];
    const int*   rel_edge_index = (const int*)d_in[2];
    const int*   rel_edge_type  = (const int*)d_in[3];
    const int*   batch_triples  = (const int*)d_in[4];
    const float* rel_emb        = (const float*)d_in[5];
    const float* rel_W          = (const float*)d_in[6];
    const float* rel_b          = (const float*)d_in[7];
    const float* rel_g          = (const float*)d_in[8];
    const float* rel_beta       = (const float*)d_in[9];
    const float* proj_W1        = (const float*)d_in[10];
    const float* proj_b1        = (const float*)d_in[11];
    const float* proj_W2        = (const float*)d_in[12];
    const float* proj_b2        = (const float*)d_in[13];
    const float* ent_W          = (const float*)d_in[14];
    const float* ent_b          = (const float*)d_in[15];
    const float* ent_g          = (const float*)d_in[16];
    const float* ent_beta       = (const float*)d_in[17];
    const float* mlp_W1         = (const float*)d_in[18];
    const float* mlp_b1         = (const float*)d_in[19];
    const float* mlp_W2         = (const float*)d_in[20];
    const float* mlp_b2         = (const float*)d_in[21];

    float* ws = (float*)d_ws;
    float* xrel0    = ws;                                   // B*R*D
    float* xrel1    = xrel0    + BB * RR * DD;              // B*R*D
    float* rel_buf4 = xrel1    + BB * RR * DD;              // 4*B*R*D
    float* query    = rel_buf4 + 4 * BB * RR * DD;          // B*D
    int*   deg      = (int*)(query + BB * DD);              // N
    unsigned* fixbit = (unsigned*)(deg + NN);               // NFB
    int*   rowptr   = (int*)(fixbit + NFB);                 // N+1
    int*   cursor   = rowptr + NN + 1;                      // N
    int*   pack     = cursor + NN;                          // E
    int*   fixlist  = pack + EE;                            // BB*FCAP
    int*   fixcnt   = fixlist + BB * FCAP;                  // BB
    int*   bsum     = fixcnt + BB;                          // NSB (pad 256)
    int*   boff     = bsum + 256;                           // NSB (pad 256)
    int*   rptrR    = boff + 256;                           // RR+1 (pad 66)
    int*   rpackR   = rptrR + 66;                           // ERE
    uintptr_t wp = (uintptr_t)(rpackR + ERE);
    wp = (wp + 15) & ~(uintptr_t)15;
    unsigned short* wbf    = (unsigned short*)wp;           // 3*16*64*8
    unsigned short* x_bfiA = wbf + 3 * 16 * 64 * 8;         // B*N*D bf16 [v][b][d]
    unsigned short* x_bfiB = x_bfiA + (size_t)BB * NN * DD; // B*N*D bf16 [v][b][d]

    // ---- CSR build + fixlist/bitmap + rel CSR + W fragment pack ----
    hipMemsetAsync(deg, 0, sizeof(int) * (NN + NFB), stream);  // deg + fixbit
    hipMemsetAsync(fixcnt, 0, sizeof(int) * BB, stream);
    edge_scan<<<(EE + 255) / 256, 256, 0, stream>>>(
        edge_index, edge_type, batch_triples, deg, fixlist, fixcnt, fixbit);
    scan_a<<<NSB, 256, 0, stream>>>(deg, bsum);
    setup_small<<<50, 256, 0, stream>>>(
        bsum, boff, rowptr, rel_edge_index, rel_edge_type, rptrR, rpackR,
        ent_W, wbf);
    scan_c<<<NSB, 256, 0, stream>>>(deg, boff, rowptr, cursor);
    csr_fill<<<(EE + 255) / 256, 256, 0, stream>>>(edge_index, edge_type, cursor, pack);

    // ---- relation stage ----
    rel_layer0<<<BB * RR / 4, 256, 0, stream>>>(
        rptrR, rpackR, batch_triples, rel_emb,
        rel_W, rel_b, rel_g, rel_beta, xrel1);
    for (int l = 1; l < LL; ++l) {
        const float* xin = (l & 1) ? xrel1 : xrel0;
        float* xout = (l & 1) ? xrel0 : xrel1;
        rel_layer<<<BB * RR / 4, 256, 0, stream>>>(
            rptrR, rpackR, batch_triples, rel_emb + l * RT * DD,
            rel_W + l * 2 * DD * DD, rel_b + l * DD,
            rel_g + l * DD, rel_beta + l * DD, xin, xout);
    }
    float* rel_repr = xrel0;
    rel_projq<<<4 * BB * RR / 4, 256, 0, stream>>>(
        rel_repr, batch_triples, proj_W1, proj_b1, proj_W2, proj_b2,
        rel_buf4, query);

    // ---- entity stage: layer 0 (seed union-fixset rows, then fix) ----
    l0_seed<<<(BB * FCAP) / 4, 256, 0, stream>>>(
        fixlist, fixcnt, ent_b, ent_g, ent_beta, x_bfiA);
    l0_fix<<<(BB * FCAP) / 4, 256, 0, stream>>>(
        batch_triples, fixlist, fixcnt, query, rel_buf4,
        ent_W, ent_b, ent_g, ent_beta, x_bfiA);

    // ---- entity stage: layer 1 (constant fast path) ----
    gather_dense_l1<<<NN / 16, 256, 0, stream>>>(
        rowptr, pack, batch_triples, fixbit, x_bfiA,
        rel_buf4 + 1 * BB * RR * DD, query,
        wbf + 0 * 16 * 64 * 8,
        ent_b + 1 * DD, ent_g + 1 * DD, ent_beta + 1 * DD,
        ent_b, ent_g, ent_beta, x_bfiB);

    // ---- entity stage: layers 2..3 ----
    unsigned short* bufs[2] = {x_bfiA, x_bfiB};
    for (int l = 2; l < LL; ++l) {
        gather_dense<<<NN / 16, 256, 0, stream>>>(
            rowptr, pack, batch_triples, bufs[(l - 1) & 1],
            rel_buf4 + l * BB * RR * DD, query,
            wbf + (size_t)(l - 1) * 16 * 64 * 8,
            ent_b + l * DD, ent_g + l * DD, ent_beta + l * DD,
            bufs[l & 1]);
    }

    readout<<<BB * KK, 2 * DD, 0, stream>>>(batch_triples, bufs[1], query,
                                            mlp_W1, mlp_b1, mlp_W2, mlp_b2,
                                            (float*)d_out);
}

// Round 17
// 198.405 us; speedup vs baseline: 1.6294x; 1.4009x over previous
//
#include <hip/hip_runtime.h>
#include <hip/hip_bf16.h>

#define BB 4
#define KK 16
#define NN 50000
#define EE 300000
#define RR 64
#define ERE 2048
#define RT 4
#define DD 64
#define LL 4
#define FCAP 256
#define NSB 196   // (NN+255)/256
#define NFB 1568  // bitmap ints, >= (NN+31)/32
#define S3CAP 16
#define S2CAP 1024
#define S1CAP 8192

typedef float f32x4 __attribute__((ext_vector_type(4)));

__device__ __forceinline__ float wsum64(float v) {
#pragma unroll
    for (int off = 32; off > 0; off >>= 1) v += __shfl_xor(v, off, 64);
    return v;
}

__device__ __forceinline__ unsigned short f2bf_rne(float f) {
    unsigned u = __builtin_bit_cast(unsigned, f);
    return (unsigned short)((u + 0x7FFFu + ((u >> 16) & 1u)) >> 16);
}

__device__ __forceinline__ float bf2f(unsigned short h) {
    unsigned u = ((unsigned)h) << 16;
    return __builtin_bit_cast(float, u);
}

// ==================== fused edge pass: histogram + fixlist + fix bitmap ======
__global__ __launch_bounds__(256) void edge_scan(
    const int* __restrict__ edge_index, const int* __restrict__ edge_type,
    const int* __restrict__ bt, int* __restrict__ deg,
    int* __restrict__ fixlist, int* __restrict__ cnt,
    unsigned* __restrict__ fixbit)
{
    int e = blockIdx.x * 256 + threadIdx.x;
    if (e < BB) {
        int h0 = bt[e * KK * 3];
        int pos = atomicAdd(&cnt[e], 1);
        if (pos < FCAP) fixlist[e * FCAP + pos] = h0 | (int)(0xFFFFu << 16);
        atomicOr(&fixbit[h0 >> 5], 1u << (h0 & 31));
    }
    if (e >= EE) return;
    int s = edge_index[e];
    int d = edge_index[EE + e];
    int t = edge_type[e];
    atomicAdd(&deg[d], 1);
#pragma unroll
    for (int b = 0; b < BB; ++b) {
        int h0 = bt[b * KK * 3];
        if (s == h0) {
            int pos = atomicAdd(&cnt[b], 1);
            if (pos < FCAP) fixlist[b * FCAP + pos] = d | (t << 16);
            atomicOr(&fixbit[d >> 5], 1u << (d & 31));
        }
    }
}

// ==================== scan pipeline ==========================================
__global__ __launch_bounds__(256) void scan_a(
    const int* __restrict__ deg, int* __restrict__ bsum)
{
    int i = blockIdx.x * 256 + threadIdx.x;
    int v = (i < NN) ? deg[i] : 0;
    int s = v;
#pragma unroll
    for (int off = 32; off > 0; off >>= 1) s += __shfl_xor(s, off, 64);
    __shared__ int ls[4];
    if ((threadIdx.x & 63) == 0) ls[threadIdx.x >> 6] = s;
    __syncthreads();
    if (threadIdx.x == 0) bsum[blockIdx.x] = ls[0] + ls[1] + ls[2] + ls[3];
}

// fused: block 0 = scan_b; block 1 = rel graph CSR
__global__ __launch_bounds__(256) void setup_small(
    const int* __restrict__ bsum, int* __restrict__ boff, int* __restrict__ rowptr,
    const int* __restrict__ rel_edge_index, const int* __restrict__ rel_edge_type,
    int* __restrict__ rptr, int* __restrict__ rpack)
{
    int t = threadIdx.x;
    if (blockIdx.x == 0) {
        __shared__ int tmp[256];
        int v = (t < NSB) ? bsum[t] : 0;
        tmp[t] = v;
        __syncthreads();
        for (int off = 1; off < 256; off <<= 1) {
            int u = (t >= off) ? tmp[t - off] : 0;
            __syncthreads();
            tmp[t] += u;
            __syncthreads();
        }
        if (t < NSB) boff[t] = tmp[t] - v;
        if (t == 0) rowptr[NN] = EE;
    } else {
        __shared__ int hdeg[RR];
        __shared__ int hcur[RR];
        if (t < RR) hdeg[t] = 0;
        __syncthreads();
        for (int e = t; e < ERE; e += 256) atomicAdd(&hdeg[rel_edge_index[ERE + e]], 1);
        __syncthreads();
        if (t == 0) {
            int run = 0;
            for (int r = 0; r < RR; ++r) { hcur[r] = run; rptr[r] = run; run += hdeg[r]; }
            rptr[RR] = run;
        }
        __syncthreads();
        for (int e = t; e < ERE; e += 256) {
            int s = rel_edge_index[e];
            int d = rel_edge_index[ERE + e];
            int ty = rel_edge_type[e];
            int pos = atomicAdd(&hcur[d], 1);
            rpack[pos] = s | (ty << 16);
        }
    }
}

__global__ __launch_bounds__(256) void scan_c(
    const int* __restrict__ deg, const int* __restrict__ boff,
    int* __restrict__ rowptr, int* __restrict__ cursor)
{
    __shared__ int tmp[256];
    int t = threadIdx.x;
    int i = blockIdx.x * 256 + t;
    int v = (i < NN) ? deg[i] : 0;
    tmp[t] = v;
    __syncthreads();
    for (int off = 1; off < 256; off <<= 1) {
        int u = (t >= off) ? tmp[t - off] : 0;
        __syncthreads();
        tmp[t] += u;
        __syncthreads();
    }
    if (i < NN) {
        int excl = tmp[t] - v + boff[blockIdx.x];
        rowptr[i] = excl;
        cursor[i] = excl;
    }
}

__global__ __launch_bounds__(256) void csr_fill(
    const int* __restrict__ edge_index, const int* __restrict__ edge_type,
    int* __restrict__ cursor, int* __restrict__ pack)
{
    int e = blockIdx.x * 256 + threadIdx.x;
    if (e >= EE) return;
    int s = edge_index[e];
    int d = edge_index[EE + e];
    int t = edge_type[e];
    int pos = atomicAdd(&cursor[d], 1);
    pack[pos] = s | (t << 16);  // src < 2^16, et < 64
}

// ==================== frontier construction ==================================
__global__ __launch_bounds__(64) void fr_init(
    const int* __restrict__ bt, unsigned* __restrict__ bm3,
    int* __restrict__ lst3, int* __restrict__ cnt3)
{
    int i = threadIdx.x;  // 0..63 = B*K
    int b = i / KK, k = i - b * KK;
    int t = bt[(b * KK + k) * 3 + 1];
    unsigned old = atomicOr(&bm3[b * NFB + (t >> 5)], 1u << (t & 31));
    if (!((old >> (t & 31)) & 1)) {
        int pos = atomicAdd(&cnt3[b], 1);
        if (pos < S3CAP) lst3[b * S3CAP + pos] = t;
    }
}

// out-set = in-set ∪ in-neighbors(in-set); wave per (b, idx)
__global__ __launch_bounds__(256) void fr_expand(
    const int* __restrict__ rowptr, const int* __restrict__ pack,
    const int* __restrict__ lstIn, const int* __restrict__ cntIn, int INCAP,
    unsigned* __restrict__ bmOut, int* __restrict__ lstOut,
    int* __restrict__ cntOut, int OUTCAP)
{
    int gw = blockIdx.x * 4 + (int)(threadIdx.x >> 6);
    int lane = threadIdx.x & 63;
    int b = gw / INCAP, idx = gw - b * INCAP;
    if (idx >= cntIn[b]) return;
    int v = lstIn[b * INCAP + idx];
    if (lane == 0) {
        unsigned old = atomicOr(&bmOut[b * NFB + (v >> 5)], 1u << (v & 31));
        if (!((old >> (v & 31)) & 1)) {
            int pos = atomicAdd(&cntOut[b], 1);
            if (pos < OUTCAP) lstOut[b * OUTCAP + pos] = v;
        }
    }
    int beg = rowptr[v], end = rowptr[v + 1];
    for (int j = beg + lane; j < end; j += 64) {
        int s = pack[j] & 0xFFFF;
        unsigned old = atomicOr(&bmOut[b * NFB + (s >> 5)], 1u << (s & 31));
        if (!((old >> (s & 31)) & 1)) {
            int pos = atomicAdd(&cntOut[b], 1);
            if (pos < OUTCAP) lstOut[b * OUTCAP + pos] = s;
        }
    }
}

// ==================== relation stage =========================================
__global__ __launch_bounds__(256) void rel_layer0(
    const int* __restrict__ rptr, const int* __restrict__ rpack,
    const int* __restrict__ bt, const float* __restrict__ emb,
    const float* __restrict__ W, const float* __restrict__ bias,
    const float* __restrict__ g, const float* __restrict__ beta,
    float* __restrict__ xout)
{
    int row = blockIdx.x * 4 + (int)(threadIdx.x >> 6);  // 0..BB*RR-1
    int lane = threadIdx.x & 63;
    int b = row >> 6, r = row & 63;
    int r0 = bt[(b * KK) * 3 + 2];
    int beg = rptr[r], end = rptr[r + 1];
    float av = (r == r0) ? 1.0f : 0.0f;
    for (int j = beg; j < end; ++j) {
        int p = rpack[j];
        if ((p & 0xFFFF) == r0) av += emb[(p >> 16) * DD + lane];
    }
    float xv = (r == r0) ? 1.0f : 0.0f;
    float acc = bias[lane];
#pragma unroll 8
    for (int k = 0; k < DD; ++k) {
        acc += __shfl(xv, k, 64) * W[k * DD + lane];
        acc += __shfl(av, k, 64) * W[(DD + k) * DD + lane];
    }
    float m = wsum64(acc) * (1.0f / DD);
    float c = acc - m;
    float v = wsum64(c * c) * (1.0f / DD);
    float o = c * rsqrtf(v + 1e-5f) * g[lane] + beta[lane];
    xout[row * DD + lane] = fmaxf(o, 0.0f) + xv;
}

__global__ __launch_bounds__(256) void rel_layer(
    const int* __restrict__ rptr, const int* __restrict__ rpack,
    const int* __restrict__ bt, const float* __restrict__ emb,
    const float* __restrict__ W, const float* __restrict__ bias,
    const float* __restrict__ g, const float* __restrict__ beta,
    const float* __restrict__ xin, float* __restrict__ xout)
{
    int row = blockIdx.x * 4 + (int)(threadIdx.x >> 6);  // 0..BB*RR-1
    int lane = threadIdx.x & 63;
    int b = row >> 6, r = row & 63;
    int r0 = bt[(b * KK) * 3 + 2];
    int beg = rptr[r], end = rptr[r + 1];
    const float* xb = xin + b * RR * DD;
    float av = (r == r0) ? 1.0f : 0.0f;
    for (int j = beg; j < end; ++j) {
        int p = rpack[j];
        av += xb[(p & 0xFFFF) * DD + lane] * emb[(p >> 16) * DD + lane];
    }
    float xv = xin[row * DD + lane];
    float acc = bias[lane];
#pragma unroll 8
    for (int k = 0; k < DD; ++k) {
        acc += __shfl(xv, k, 64) * W[k * DD + lane];
        acc += __shfl(av, k, 64) * W[(DD + k) * DD + lane];
    }
    float m = wsum64(acc) * (1.0f / DD);
    float c = acc - m;
    float v = wsum64(c * c) * (1.0f / DD);
    float o = c * rsqrtf(v + 1e-5f) * g[lane] + beta[lane];
    xout[row * DD + lane] = fmaxf(o, 0.0f) + xv;
}

// all-4-layer projection + query extraction (block 0)
__global__ __launch_bounds__(256) void rel_projq(
    const float* __restrict__ rel_repr, const int* __restrict__ bt,
    const float* __restrict__ W1, const float* __restrict__ b1,
    const float* __restrict__ W2, const float* __restrict__ b2,
    float* __restrict__ rel_buf4, float* __restrict__ query)
{
    int grow = blockIdx.x * 4 + (int)(threadIdx.x >> 6);  // 0..4*B*R-1
    int lane = threadIdx.x & 63;
    int l = grow / (BB * RR);
    int row = grow - l * (BB * RR);
    const float* xr = &rel_repr[row * DD];
    const float* w1 = W1 + l * DD * DD;
    const float* w2 = W2 + l * DD * DD;
    float h = b1[l * DD + lane];
#pragma unroll 8
    for (int k = 0; k < DD; ++k) h += xr[k] * w1[k * DD + lane];
    h = fmaxf(h, 0.0f);
    float o = b2[l * DD + lane];
#pragma unroll 8
    for (int k = 0; k < DD; ++k) o += __shfl(h, k, 64) * w2[k * DD + lane];
    rel_buf4[grow * DD + lane] = o;
    if (blockIdx.x == 0) {
        int i = threadIdx.x;  // 0..255 = B*D
        int b = i / DD, d = i - b * DD;
        int r0 = bt[(b * KK) * 3 + 2];
        query[b * DD + d] = rel_repr[(b * RR + r0) * DD + d];
    }
}

// ==================== entity stage layer 0 (sparse) ==========================
__global__ __launch_bounds__(256) void l0_seed(
    const int* __restrict__ fixlist, const int* __restrict__ cnt,
    const float* __restrict__ b0, const float* __restrict__ g0,
    const float* __restrict__ be0, unsigned short* __restrict__ x_bfi)
{
    int gidx = blockIdx.x * 4 + (int)(threadIdx.x >> 6);  // (bl, i)
    int lane = threadIdx.x & 63;
    float bv = b0[lane];
    float m = wsum64(bv) * (1.0f / DD);
    float c = bv - m;
    float v = wsum64(c * c) * (1.0f / DD);
    float dvec = fmaxf(c * rsqrtf(v + 1e-5f) * g0[lane] + be0[lane], 0.0f);
    int bl = gidx / FCAP, i = gidx - bl * FCAP;
    int nc = min(cnt[bl], FCAP);
    if (i >= nc) return;
    int vx = fixlist[bl * FCAP + i] & 0xFFFF;
    int b = lane >> 4, d0 = (lane & 15) * 4;
    ushort4 o;
    o.x = f2bf_rne(__shfl(dvec, d0 + 0, 64));
    o.y = f2bf_rne(__shfl(dvec, d0 + 1, 64));
    o.z = f2bf_rne(__shfl(dvec, d0 + 2, 64));
    o.w = f2bf_rne(__shfl(dvec, d0 + 3, 64));
    *(ushort4*)&x_bfi[((size_t)vx * BB + b) * DD + d0] = o;
}

__global__ __launch_bounds__(256) void l0_fix(
    const int* __restrict__ bt, const int* __restrict__ fixlist,
    const int* __restrict__ cnt, const float* __restrict__ query,
    const float* __restrict__ rel_buf,
    const float* __restrict__ W0, const float* __restrict__ b0,
    const float* __restrict__ g0, const float* __restrict__ be0,
    unsigned short* __restrict__ x_bfi)
{
    int gidx = blockIdx.x * 4 + (threadIdx.x >> 6);  // 0..BB*FCAP-1
    int lane = threadIdx.x & 63;
    int b = gidx / FCAP, i = gidx - b * FCAP;
    int nc = min(cnt[b], FCAP);
    if (i >= nc) return;
    unsigned ent = (unsigned)fixlist[b * FCAP + i];
    int v = (int)(ent & 0xFFFFu);
    int h0 = bt[b * KK * 3];
    float q = query[b * DD + lane];
    float agg = (v == h0) ? q : 0.0f;
    for (int j = 0; j < nc; ++j) {
        unsigned ej = (unsigned)fixlist[b * FCAP + j];
        if ((int)(ej & 0xFFFFu) == v) {
            unsigned et = ej >> 16;
            if (et != 0xFFFFu)
                agg += q * rel_buf[(b * RR + (int)et) * DD + lane];
        }
    }
    float xr = (v == h0) ? q : 0.0f;
    float acc = b0[lane];
#pragma unroll 8
    for (int k = 0; k < DD; ++k) {
        acc += __shfl(xr, k, 64) * W0[k * DD + lane];
        acc += __shfl(agg, k, 64) * W0[(DD + k) * DD + lane];
    }
    float m = wsum64(acc) * (1.0f / DD);
    float c = acc - m;
    float vv = wsum64(c * c) * (1.0f / DD);
    float res = fmaxf(c * rsqrtf(vv + 1e-5f) * g0[lane] + be0[lane], 0.0f) + xr;
    x_bfi[((size_t)v * BB + b) * DD + lane] = f2bf_rne(res);
}

// ==================== list-based conv layer (layers 2,3) =====================
// wave per (b, i): v = lst[b][i]; gather + dense + LN + relu + residual
__global__ __launch_bounds__(256) void list_layer(
    const int* __restrict__ rowptr, const int* __restrict__ pack,
    const int* __restrict__ bt,
    const int* __restrict__ lst, const int* __restrict__ cnt, int CAP,
    const unsigned short* __restrict__ xin,
    const float* __restrict__ rel_buf, const float* __restrict__ query,
    const float* __restrict__ W, const float* __restrict__ bias,
    const float* __restrict__ g, const float* __restrict__ beta,
    unsigned short* __restrict__ xout)
{
    int gw = blockIdx.x * 4 + (int)(threadIdx.x >> 6);
    int lane = threadIdx.x & 63;
    int b = gw / CAP, i = gw - b * CAP;
    if (i >= cnt[b]) return;
    int v = lst[b * CAP + i];
    const float* rb = rel_buf + b * RR * DD;
    int h0 = bt[b * KK * 3];
    int beg = rowptr[v], end = rowptr[v + 1];
    float av = 0.0f;
    for (int j = beg; j < end; ++j) {
        int p = pack[j];
        av += bf2f(xin[((size_t)(p & 0xFFFF) * BB + b) * DD + lane])
              * rb[(p >> 16) * DD + lane];
    }
    if (v == h0) av += query[b * DD + lane];
    float xv = bf2f(xin[((size_t)v * BB + b) * DD + lane]);
    float acc = bias[lane];
#pragma unroll 8
    for (int k = 0; k < DD; ++k) {
        acc += __shfl(xv, k, 64) * W[k * DD + lane];
        acc += __shfl(av, k, 64) * W[(DD + k) * DD + lane];
    }
    float m = wsum64(acc) * (1.0f / DD);
    float c = acc - m;
    float vv = wsum64(c * c) * (1.0f / DD);
    float o = c * rsqrtf(vv + 1e-5f) * g[lane] + beta[lane];
    xout[((size_t)v * BB + b) * DD + lane] = f2bf_rne(fmaxf(o, 0.0f) + xv);
}

// ==================== list-based layer 1 (constant fast path) ================
__global__ __launch_bounds__(256) void list_layer_l1(
    const int* __restrict__ rowptr, const int* __restrict__ pack,
    const int* __restrict__ bt, const unsigned* __restrict__ fixbit,
    const int* __restrict__ lst, const int* __restrict__ cnt, int CAP,
    const unsigned short* __restrict__ xin,
    const float* __restrict__ rel_buf, const float* __restrict__ query,
    const float* __restrict__ W, const float* __restrict__ bias,
    const float* __restrict__ g, const float* __restrict__ beta,
    const float* __restrict__ b0, const float* __restrict__ g0,
    const float* __restrict__ be0,
    unsigned short* __restrict__ xout)
{
    int gw = blockIdx.x * 4 + (int)(threadIdx.x >> 6);
    int lane = threadIdx.x & 63;
    int b = gw / CAP, i = gw - b * CAP;
    if (i >= cnt[b]) return;
    int v = lst[b * CAP + i];
    // dvec (bf16-rounded layer-0 default row)
    float bv = b0[lane];
    float m0 = wsum64(bv) * (1.0f / DD);
    float c0 = bv - m0;
    float v0 = wsum64(c0 * c0) * (1.0f / DD);
    float dv = bf2f(f2bf_rne(
        fmaxf(c0 * rsqrtf(v0 + 1e-5f) * g0[lane] + be0[lane], 0.0f)));
    const float* rb = rel_buf + b * RR * DD;
    int h0 = bt[b * KK * 3];
    int beg = rowptr[v], end = rowptr[v + 1];
    float ac = 0.0f, ar = 0.0f;
    for (int j = beg; j < end; ++j) {
        int p = pack[j];
        int s = p & 0xFFFF;
        float r = rb[(p >> 16) * DD + lane];
        if ((fixbit[s >> 5] >> (s & 31)) & 1)
            ac += bf2f(xin[((size_t)s * BB + b) * DD + lane]) * r;
        else
            ar += r;
    }
    float av = ac + dv * ar;
    if (v == h0) av += query[b * DD + lane];
    bool fx = (fixbit[v >> 5] >> (v & 31)) & 1;
    float xv = fx ? bf2f(xin[((size_t)v * BB + b) * DD + lane]) : dv;
    float acc = bias[lane];
#pragma unroll 8
    for (int k = 0; k < DD; ++k) {
        acc += __shfl(xv, k, 64) * W[k * DD + lane];
        acc += __shfl(av, k, 64) * W[(DD + k) * DD + lane];
    }
    float m = wsum64(acc) * (1.0f / DD);
    float c = acc - m;
    float vv = wsum64(c * c) * (1.0f / DD);
    float o = c * rsqrtf(vv + 1e-5f) * g[lane] + beta[lane];
    xout[((size_t)v * BB + b) * DD + lane] = f2bf_rne(fmaxf(o, 0.0f) + xv);
}

// ==================== readout ================================================
__global__ __launch_bounds__(128) void readout(
    const int* __restrict__ bt, const unsigned short* __restrict__ x_bfi,
    const float* __restrict__ query,
    const float* __restrict__ W1, const float* __restrict__ b1,
    const float* __restrict__ W2, const float* __restrict__ b2,
    float* __restrict__ out)
{
    int b = blockIdx.x / KK, k = blockIdx.x - b * KK;
    int t = bt[(b * KK + k) * 3 + 1];
    __shared__ float feat[2 * DD];
    __shared__ float red[2 * DD];
    int j = threadIdx.x;
    if (j < DD) feat[j] = bf2f(x_bfi[((size_t)t * BB + b) * DD + j]);
    else        feat[j] = query[b * DD + (j - DD)];
    __syncthreads();
    float h = b1[j];
#pragma unroll 8
    for (int i = 0; i < 2 * DD; ++i) h += feat[i] * W1[i * 2 * DD + j];
    h = fmaxf(h, 0.0f);
    red[j] = h * W2[j];
    __syncthreads();
    for (int s = 64; s > 0; s >>= 1) {
        if (j < s) red[j] += red[j + s];
        __syncthreads();
    }
    if (j == 0) out[blockIdx.x] = red[0] + b2[0];
}

extern "C" void kernel_launch(void* const* d_in, const int* in_sizes, int n_in,
                              void* d_out, int out_size, void* d_ws, size_t ws_size,
                              hipStream_t stream) {
    const int*   edge_index     = (const int*)d_in[0];
    const int*   edge_type      = (const int*)d_in[1];
    const int*   rel_edge_index = (const int*)d_in[2];
    const int*   rel_edge_type  = (const int*)d_in[3];
    const int*   batch_triples  = (const int*)d_in[4];
    const float* rel_emb        = (const float*)d_in[5];
    const float* rel_W          = (const float*)d_in[6];
    const float* rel_b          = (const float*)d_in[7];
    const float* rel_g          = (const float*)d_in[8];
    const float* rel_beta       = (const float*)d_in[9];
    const float* proj_W1        = (const float*)d_in[10];
    const float* proj_b1        = (const float*)d_in[11];
    const float* proj_W2        = (const float*)d_in[12];
    const float* proj_b2        = (const float*)d_in[13];
    const float* ent_W          = (const float*)d_in[14];
    const float* ent_b          = (const float*)d_in[15];
    const float* ent_g          = (const float*)d_in[16];
    const float* ent_beta       = (const float*)d_in[17];
    const float* mlp_W1         = (const float*)d_in[18];
    const float* mlp_b1         = (const float*)d_in[19];
    const float* mlp_W2         = (const float*)d_in[20];
    const float* mlp_b2         = (const float*)d_in[21];

    float* ws = (float*)d_ws;
    float* xrel0    = ws;                                   // B*R*D
    float* xrel1    = xrel0    + BB * RR * DD;              // B*R*D
    float* rel_buf4 = xrel1    + BB * RR * DD;              // 4*B*R*D
    float* query    = rel_buf4 + 4 * BB * RR * DD;          // B*D
    // --- zeroed region (one memset) ---
    int*      deg    = (int*)(query + BB * DD);             // NN
    unsigned* fixbit = (unsigned*)(deg + NN);               // NFB
    unsigned* bm3    = fixbit + NFB;                        // BB*NFB
    unsigned* bm2    = bm3 + BB * NFB;                      // BB*NFB
    unsigned* bm1    = bm2 + BB * NFB;                      // BB*NFB
    int*      cnt3   = (int*)(bm1 + BB * NFB);              // BB
    int*      cnt2   = cnt3 + BB;                           // BB
    int*      cnt1   = cnt2 + BB;                           // BB
    int*      fixcnt = cnt1 + BB;                           // BB
    const size_t ZN  = (size_t)NN + NFB + 3 * BB * NFB + 4 * BB;
    // --- end zeroed region ---
    int* rowptr  = fixcnt + BB;                             // NN+1
    int* cursor  = rowptr + NN + 1;                         // NN
    int* pack    = cursor + NN;                             // EE
    int* fixlist = pack + EE;                               // BB*FCAP
    int* bsum    = fixlist + BB * FCAP;                     // 256
    int* boff    = bsum + 256;                              // 256
    int* rptrR   = boff + 256;                              // 66
    int* rpackR  = rptrR + 66;                              // ERE
    int* lst3    = rpackR + ERE;                            // BB*S3CAP
    int* lst2    = lst3 + BB * S3CAP;                       // BB*S2CAP
    int* lst1    = lst2 + BB * S2CAP;                       // BB*S1CAP
    uintptr_t wp = (uintptr_t)(lst1 + BB * S1CAP);
    wp = (wp + 15) & ~(uintptr_t)15;
    unsigned short* x_bfiA = (unsigned short*)wp;           // B*N*D bf16 [v][b][d]
    unsigned short* x_bfiB = x_bfiA + (size_t)BB * NN * DD; // B*N*D bf16 [v][b][d]

    // ---- zero counters/bitmaps, build CSR + fixlist + frontier base ----
    hipMemsetAsync(deg, 0, sizeof(int) * ZN, stream);
    edge_scan<<<(EE + 255) / 256, 256, 0, stream>>>(
        edge_index, edge_type, batch_triples, deg, fixlist, fixcnt, fixbit);
    scan_a<<<NSB, 256, 0, stream>>>(deg, bsum);
    setup_small<<<2, 256, 0, stream>>>(
        bsum, boff, rowptr, rel_edge_index, rel_edge_type, rptrR, rpackR);
    scan_c<<<NSB, 256, 0, stream>>>(deg, boff, rowptr, cursor);
    csr_fill<<<(EE + 255) / 256, 256, 0, stream>>>(edge_index, edge_type, cursor, pack);

    // ---- frontier: S3 = targets; S2 = S3 ∪ N(S3); S1 = S2 ∪ N(S2) ----
    fr_init<<<1, 64, 0, stream>>>(batch_triples, bm3, lst3, cnt3);
    fr_expand<<<BB * S3CAP / 4, 256, 0, stream>>>(
        rowptr, pack, lst3, cnt3, S3CAP, bm2, lst2, cnt2, S2CAP);
    fr_expand<<<BB * S2CAP / 4, 256, 0, stream>>>(
        rowptr, pack, lst2, cnt2, S2CAP, bm1, lst1, cnt1, S1CAP);

    // ---- relation stage ----
    rel_layer0<<<BB * RR / 4, 256, 0, stream>>>(
        rptrR, rpackR, batch_triples, rel_emb,
        rel_W, rel_b, rel_g, rel_beta, xrel1);
    for (int l = 1; l < LL; ++l) {
        const float* xin = (l & 1) ? xrel1 : xrel0;
        float* xout = (l & 1) ? xrel0 : xrel1;
        rel_layer<<<BB * RR / 4, 256, 0, stream>>>(
            rptrR, rpackR, batch_triples, rel_emb + l * RT * DD,
            rel_W + l * 2 * DD * DD, rel_b + l * DD,
            rel_g + l * DD, rel_beta + l * DD, xin, xout);
    }
    float* rel_repr = xrel0;
    rel_projq<<<4 * BB * RR / 4, 256, 0, stream>>>(
        rel_repr, batch_triples, proj_W1, proj_b1, proj_W2, proj_b2,
        rel_buf4, query);

    // ---- entity layer 0: seed union-fixset rows + exact fix rows ----
    l0_seed<<<(BB * FCAP) / 4, 256, 0, stream>>>(
        fixlist, fixcnt, ent_b, ent_g, ent_beta, x_bfiA);
    l0_fix<<<(BB * FCAP) / 4, 256, 0, stream>>>(
        batch_triples, fixlist, fixcnt, query, rel_buf4,
        ent_W, ent_b, ent_g, ent_beta, x_bfiA);

    // ---- entity layer 1 at S1 (constant fast path), A -> B ----
    list_layer_l1<<<BB * S1CAP / 4, 256, 0, stream>>>(
        rowptr, pack, batch_triples, fixbit, lst1, cnt1, S1CAP,
        x_bfiA, rel_buf4 + 1 * BB * RR * DD, query,
        ent_W + 1 * 2 * DD * DD, ent_b + 1 * DD, ent_g + 1 * DD,
        ent_beta + 1 * DD, ent_b, ent_g, ent_beta, x_bfiB);

    // ---- entity layer 2 at S2, B -> A ----
    list_layer<<<BB * S2CAP / 4, 256, 0, stream>>>(
        rowptr, pack, batch_triples, lst2, cnt2, S2CAP,
        x_bfiB, rel_buf4 + 2 * BB * RR * DD, query,
        ent_W + 2 * 2 * DD * DD, ent_b + 2 * DD, ent_g + 2 * DD,
        ent_beta + 2 * DD, x_bfiA);

    // ---- entity layer 3 at S3, A -> B ----
    list_layer<<<BB * S3CAP / 4, 256, 0, stream>>>(
        rowptr, pack, batch_triples, lst3, cnt3, S3CAP,
        x_bfiA, rel_buf4 + 3 * BB * RR * DD, query,
        ent_W + 3 * 2 * DD * DD, ent_b + 3 * DD, ent_g + 3 * DD,
        ent_beta + 3 * DD, x_bfiB);

    readout<<<BB * KK, 2 * DD, 0, stream>>>(batch_triples, x_bfiB, query,
                                            mlp_W1, mlp_b1, mlp_W2, mlp_b2,
                                            (float*)d_out);
}

// Round 18
// 187.095 us; speedup vs baseline: 1.7279x; 1.0604x over previous
//
#include <hip/hip_runtime.h>
#include <hip/hip_bf16.h>

#define BB 4
#define KK 16
#define NN 50000
#define EE 300000
#define RR 64
#define ERE 2048
#define RT 4
#define DD 64
#define LL 4
#define FCAP 256
#define NFB 1568   // bitmap ints, >= (NN+31)/32
#define S3CAP 16
#define S2CAP 1024
#define S1CAP 4096
#define CAPDEG 64  // fixed-slot CSR width (max in-degree; Poisson(6) tail << 64)
#define RCAP 128   // rel-graph slot width
#define NEB 1172   // (EE+255)/256 entity-edge blocks

typedef float f32x4 __attribute__((ext_vector_type(4)));

__device__ __forceinline__ float wsum64(float v) {
#pragma unroll
    for (int off = 32; off > 0; off >>= 1) v += __shfl_xor(v, off, 64);
    return v;
}

__device__ __forceinline__ unsigned short f2bf_rne(float f) {
    unsigned u = __builtin_bit_cast(unsigned, f);
    return (unsigned short)((u + 0x7FFFu + ((u >> 16) & 1u)) >> 16);
}

__device__ __forceinline__ float bf2f(unsigned short h) {
    unsigned u = ((unsigned)h) << 16;
    return __builtin_bit_cast(float, u);
}

// ==== one fused edge pass: slot-CSR + fixlist/bitmap + S3 init + rel-CSR ====
__global__ __launch_bounds__(256) void edge_scan(
    const int* __restrict__ edge_index, const int* __restrict__ edge_type,
    const int* __restrict__ bt,
    int* __restrict__ deg, int* __restrict__ pack,
    int* __restrict__ fixlist, int* __restrict__ fixcnt,
    unsigned* __restrict__ fixbit,
    unsigned* __restrict__ bm3, int* __restrict__ lst3, int* __restrict__ cnt3,
    const int* __restrict__ rel_edge_index, const int* __restrict__ rel_edge_type,
    int* __restrict__ rdeg, int* __restrict__ rpack)
{
    int gid = blockIdx.x;
    if (gid >= NEB) {  // rel-graph edges
        int e = (gid - NEB) * 256 + threadIdx.x;
        if (e < ERE) {
            int s = rel_edge_index[e];
            int d = rel_edge_index[ERE + e];
            int ty = rel_edge_type[e];
            int slot = atomicAdd(&rdeg[d], 1);
            if (slot < RCAP) rpack[d * RCAP + slot] = s | (ty << 16);
        }
        return;
    }
    int e = gid * 256 + threadIdx.x;
    if (e < BB * KK) {  // S3 frontier init (targets)
        int b = e / KK, k = e - b * KK;
        int t = bt[(b * KK + k) * 3 + 1];
        unsigned old = atomicOr(&bm3[b * NFB + (t >> 5)], 1u << (t & 31));
        if (!((old >> (t & 31)) & 1)) {
            int pos = atomicAdd(&cnt3[b], 1);
            if (pos < S3CAP) lst3[b * S3CAP + pos] = t;
        }
    }
    if (e < BB) {  // h0 self-marker for layer-0 fixlist
        int h0 = bt[e * KK * 3];
        int pos = atomicAdd(&fixcnt[e], 1);
        if (pos < FCAP) fixlist[e * FCAP + pos] = h0 | (int)(0xFFFFu << 16);
        atomicOr(&fixbit[h0 >> 5], 1u << (h0 & 31));
    }
    if (e >= EE) return;
    int s = edge_index[e];
    int d = edge_index[EE + e];
    int t = edge_type[e];
    int slot = atomicAdd(&deg[d], 1);
    if (slot < CAPDEG) pack[(size_t)d * CAPDEG + slot] = s | (t << 16);
#pragma unroll
    for (int b = 0; b < BB; ++b) {
        int h0 = bt[b * KK * 3];
        if (s == h0) {
            int pos = atomicAdd(&fixcnt[b], 1);
            if (pos < FCAP) fixlist[b * FCAP + pos] = d | (t << 16);
            atomicOr(&fixbit[d >> 5], 1u << (d & 31));
        }
    }
}

// ==================== frontier expansion =====================================
__global__ __launch_bounds__(256) void fr_expand(
    const int* __restrict__ deg, const int* __restrict__ pack,
    const int* __restrict__ lstIn, const int* __restrict__ cntIn, int INCAP,
    unsigned* __restrict__ bmOut, int* __restrict__ lstOut,
    int* __restrict__ cntOut, int OUTCAP)
{
    int gw = blockIdx.x * 4 + (int)(threadIdx.x >> 6);
    int lane = threadIdx.x & 63;
    int b = gw / INCAP, idx = gw - b * INCAP;
    if (idx >= cntIn[b]) return;
    int v = lstIn[b * INCAP + idx];
    if (lane == 0) {
        unsigned old = atomicOr(&bmOut[b * NFB + (v >> 5)], 1u << (v & 31));
        if (!((old >> (v & 31)) & 1)) {
            int pos = atomicAdd(&cntOut[b], 1);
            if (pos < OUTCAP) lstOut[b * OUTCAP + pos] = v;
        }
    }
    int beg = v * CAPDEG, end = beg + min(deg[v], CAPDEG);
    for (int j = beg + lane; j < end; j += 64) {
        int s = pack[j] & 0xFFFF;
        unsigned old = atomicOr(&bmOut[b * NFB + (s >> 5)], 1u << (s & 31));
        if (!((old >> (s & 31)) & 1)) {
            int pos = atomicAdd(&cntOut[b], 1);
            if (pos < OUTCAP) lstOut[b * OUTCAP + pos] = s;
        }
    }
}

// ==================== relation stage =========================================
__global__ __launch_bounds__(256) void rel_layer0(
    const int* __restrict__ rdeg, const int* __restrict__ rpack,
    const int* __restrict__ bt, const float* __restrict__ emb,
    const float* __restrict__ W, const float* __restrict__ bias,
    const float* __restrict__ g, const float* __restrict__ beta,
    float* __restrict__ xout)
{
    int row = blockIdx.x * 4 + (int)(threadIdx.x >> 6);  // 0..BB*RR-1
    int lane = threadIdx.x & 63;
    int b = row >> 6, r = row & 63;
    int r0 = bt[(b * KK) * 3 + 2];
    int beg = r * RCAP, end = beg + min(rdeg[r], RCAP);
    float av = (r == r0) ? 1.0f : 0.0f;
    for (int j = beg; j < end; ++j) {
        int p = rpack[j];
        if ((p & 0xFFFF) == r0) av += emb[(p >> 16) * DD + lane];
    }
    float xv = (r == r0) ? 1.0f : 0.0f;
    float acc = bias[lane];
#pragma unroll 8
    for (int k = 0; k < DD; ++k) {
        acc += __shfl(xv, k, 64) * W[k * DD + lane];
        acc += __shfl(av, k, 64) * W[(DD + k) * DD + lane];
    }
    float m = wsum64(acc) * (1.0f / DD);
    float c = acc - m;
    float v = wsum64(c * c) * (1.0f / DD);
    float o = c * rsqrtf(v + 1e-5f) * g[lane] + beta[lane];
    xout[row * DD + lane] = fmaxf(o, 0.0f) + xv;
}

__global__ __launch_bounds__(256) void rel_layer(
    const int* __restrict__ rdeg, const int* __restrict__ rpack,
    const int* __restrict__ bt, const float* __restrict__ emb,
    const float* __restrict__ W, const float* __restrict__ bias,
    const float* __restrict__ g, const float* __restrict__ beta,
    const float* __restrict__ xin, float* __restrict__ xout)
{
    int row = blockIdx.x * 4 + (int)(threadIdx.x >> 6);
    int lane = threadIdx.x & 63;
    int b = row >> 6, r = row & 63;
    int r0 = bt[(b * KK) * 3 + 2];
    int beg = r * RCAP, end = beg + min(rdeg[r], RCAP);
    const float* xb = xin + b * RR * DD;
    float av = (r == r0) ? 1.0f : 0.0f;
    for (int j = beg; j < end; ++j) {
        int p = rpack[j];
        av += xb[(p & 0xFFFF) * DD + lane] * emb[(p >> 16) * DD + lane];
    }
    float xv = xin[row * DD + lane];
    float acc = bias[lane];
#pragma unroll 8
    for (int k = 0; k < DD; ++k) {
        acc += __shfl(xv, k, 64) * W[k * DD + lane];
        acc += __shfl(av, k, 64) * W[(DD + k) * DD + lane];
    }
    float m = wsum64(acc) * (1.0f / DD);
    float c = acc - m;
    float v = wsum64(c * c) * (1.0f / DD);
    float o = c * rsqrtf(v + 1e-5f) * g[lane] + beta[lane];
    xout[row * DD + lane] = fmaxf(o, 0.0f) + xv;
}

// last rel layer fused with all-4-layer projection + query extraction
__global__ __launch_bounds__(256) void rel_layer3_proj(
    const int* __restrict__ rdeg, const int* __restrict__ rpack,
    const int* __restrict__ bt, const float* __restrict__ emb,
    const float* __restrict__ W, const float* __restrict__ bias,
    const float* __restrict__ g, const float* __restrict__ beta,
    const float* __restrict__ xin,
    const float* __restrict__ pW1, const float* __restrict__ pb1,
    const float* __restrict__ pW2, const float* __restrict__ pb2,
    float* __restrict__ rel_buf4, float* __restrict__ query)
{
    int row = blockIdx.x * 4 + (int)(threadIdx.x >> 6);
    int lane = threadIdx.x & 63;
    int b = row >> 6, r = row & 63;
    int r0 = bt[(b * KK) * 3 + 2];
    int beg = r * RCAP, end = beg + min(rdeg[r], RCAP);
    const float* xb = xin + b * RR * DD;
    float av = (r == r0) ? 1.0f : 0.0f;
    for (int j = beg; j < end; ++j) {
        int p = rpack[j];
        av += xb[(p & 0xFFFF) * DD + lane] * emb[(p >> 16) * DD + lane];
    }
    float xv = xin[row * DD + lane];
    float acc = bias[lane];
#pragma unroll 8
    for (int k = 0; k < DD; ++k) {
        acc += __shfl(xv, k, 64) * W[k * DD + lane];
        acc += __shfl(av, k, 64) * W[(DD + k) * DD + lane];
    }
    float m = wsum64(acc) * (1.0f / DD);
    float c = acc - m;
    float v = wsum64(c * c) * (1.0f / DD);
    float res = fmaxf(c * rsqrtf(v + 1e-5f) * g[lane] + beta[lane], 0.0f) + xv;
    // projections for this row (res is the final relation_repr row)
#pragma unroll 1
    for (int l = 0; l < LL; ++l) {
        const float* w1 = pW1 + l * DD * DD;
        const float* w2 = pW2 + l * DD * DD;
        float h = pb1[l * DD + lane];
#pragma unroll 8
        for (int k = 0; k < DD; ++k) h += __shfl(res, k, 64) * w1[k * DD + lane];
        h = fmaxf(h, 0.0f);
        float o = pb2[l * DD + lane];
#pragma unroll 8
        for (int k = 0; k < DD; ++k) o += __shfl(h, k, 64) * w2[k * DD + lane];
        rel_buf4[(l * BB * RR + row) * DD + lane] = o;
    }
    if (r == r0) query[b * DD + lane] = res;
}

// ==================== entity stage layer 0 (sparse) ==========================
__global__ __launch_bounds__(256) void l0_seed(
    const int* __restrict__ fixlist, const int* __restrict__ cnt,
    const float* __restrict__ b0, const float* __restrict__ g0,
    const float* __restrict__ be0, unsigned short* __restrict__ x_bfi)
{
    int gidx = blockIdx.x * 4 + (int)(threadIdx.x >> 6);
    int lane = threadIdx.x & 63;
    float bv = b0[lane];
    float m = wsum64(bv) * (1.0f / DD);
    float c = bv - m;
    float v = wsum64(c * c) * (1.0f / DD);
    float dvec = fmaxf(c * rsqrtf(v + 1e-5f) * g0[lane] + be0[lane], 0.0f);
    int bl = gidx / FCAP, i = gidx - bl * FCAP;
    int nc = min(cnt[bl], FCAP);
    if (i >= nc) return;
    int vx = fixlist[bl * FCAP + i] & 0xFFFF;
    int b = lane >> 4, d0 = (lane & 15) * 4;
    ushort4 o;
    o.x = f2bf_rne(__shfl(dvec, d0 + 0, 64));
    o.y = f2bf_rne(__shfl(dvec, d0 + 1, 64));
    o.z = f2bf_rne(__shfl(dvec, d0 + 2, 64));
    o.w = f2bf_rne(__shfl(dvec, d0 + 3, 64));
    *(ushort4*)&x_bfi[((size_t)vx * BB + b) * DD + d0] = o;
}

__global__ __launch_bounds__(256) void l0_fix(
    const int* __restrict__ bt, const int* __restrict__ fixlist,
    const int* __restrict__ cnt, const float* __restrict__ query,
    const float* __restrict__ rel_buf,
    const float* __restrict__ W0, const float* __restrict__ b0,
    const float* __restrict__ g0, const float* __restrict__ be0,
    unsigned short* __restrict__ x_bfi)
{
    int gidx = blockIdx.x * 4 + (threadIdx.x >> 6);
    int lane = threadIdx.x & 63;
    int b = gidx / FCAP, i = gidx - b * FCAP;
    int nc = min(cnt[b], FCAP);
    if (i >= nc) return;
    unsigned ent = (unsigned)fixlist[b * FCAP + i];
    int v = (int)(ent & 0xFFFFu);
    int h0 = bt[b * KK * 3];
    float q = query[b * DD + lane];
    float agg = (v == h0) ? q : 0.0f;
    for (int j = 0; j < nc; ++j) {
        unsigned ej = (unsigned)fixlist[b * FCAP + j];
        if ((int)(ej & 0xFFFFu) == v) {
            unsigned et = ej >> 16;
            if (et != 0xFFFFu)
                agg += q * rel_buf[(b * RR + (int)et) * DD + lane];
        }
    }
    float xr = (v == h0) ? q : 0.0f;
    float acc = b0[lane];
#pragma unroll 8
    for (int k = 0; k < DD; ++k) {
        acc += __shfl(xr, k, 64) * W0[k * DD + lane];
        acc += __shfl(agg, k, 64) * W0[(DD + k) * DD + lane];
    }
    float m = wsum64(acc) * (1.0f / DD);
    float c = acc - m;
    float vv = wsum64(c * c) * (1.0f / DD);
    float res = fmaxf(c * rsqrtf(vv + 1e-5f) * g0[lane] + be0[lane], 0.0f) + xr;
    x_bfi[((size_t)v * BB + b) * DD + lane] = f2bf_rne(res);
}

// ==================== list-based conv layer (layers 2,3) =====================
__global__ __launch_bounds__(256) void list_layer(
    const int* __restrict__ deg, const int* __restrict__ pack,
    const int* __restrict__ bt,
    const int* __restrict__ lst, const int* __restrict__ cnt, int CAP,
    const unsigned short* __restrict__ xin,
    const float* __restrict__ rel_buf, const float* __restrict__ query,
    const float* __restrict__ W, const float* __restrict__ bias,
    const float* __restrict__ g, const float* __restrict__ beta,
    unsigned short* __restrict__ xout)
{
    int gw = blockIdx.x * 4 + (int)(threadIdx.x >> 6);
    int lane = threadIdx.x & 63;
    int b = gw / CAP, i = gw - b * CAP;
    if (i >= cnt[b]) return;
    int v = lst[b * CAP + i];
    const float* rb = rel_buf + b * RR * DD;
    int h0 = bt[b * KK * 3];
    int beg = v * CAPDEG, end = beg + min(deg[v], CAPDEG);
    float av = 0.0f;
    int j = beg;
    for (; j + 1 < end; j += 2) {
        int p0 = pack[j], p1 = pack[j + 1];
        float x0 = bf2f(xin[((size_t)(p0 & 0xFFFF) * BB + b) * DD + lane]);
        float x1 = bf2f(xin[((size_t)(p1 & 0xFFFF) * BB + b) * DD + lane]);
        float r0 = rb[(p0 >> 16) * DD + lane];
        float r1 = rb[(p1 >> 16) * DD + lane];
        av += x0 * r0 + x1 * r1;
    }
    if (j < end) {
        int p0 = pack[j];
        av += bf2f(xin[((size_t)(p0 & 0xFFFF) * BB + b) * DD + lane])
              * rb[(p0 >> 16) * DD + lane];
    }
    if (v == h0) av += query[b * DD + lane];
    float xv = bf2f(xin[((size_t)v * BB + b) * DD + lane]);
    float acc = bias[lane];
#pragma unroll 8
    for (int k = 0; k < DD; ++k) {
        acc += __shfl(xv, k, 64) * W[k * DD + lane];
        acc += __shfl(av, k, 64) * W[(DD + k) * DD + lane];
    }
    float m = wsum64(acc) * (1.0f / DD);
    float c = acc - m;
    float vv = wsum64(c * c) * (1.0f / DD);
    float o = c * rsqrtf(vv + 1e-5f) * g[lane] + beta[lane];
    xout[((size_t)v * BB + b) * DD + lane] = f2bf_rne(fmaxf(o, 0.0f) + xv);
}

// ==================== list-based layer 1 (constant fast path) ================
__global__ __launch_bounds__(256) void list_layer_l1(
    const int* __restrict__ deg, const int* __restrict__ pack,
    const int* __restrict__ bt, const unsigned* __restrict__ fixbit,
    const int* __restrict__ lst, const int* __restrict__ cnt, int CAP,
    const unsigned short* __restrict__ xin,
    const float* __restrict__ rel_buf, const float* __restrict__ query,
    const float* __restrict__ W, const float* __restrict__ bias,
    const float* __restrict__ g, const float* __restrict__ beta,
    const float* __restrict__ b0, const float* __restrict__ g0,
    const float* __restrict__ be0,
    unsigned short* __restrict__ xout)
{
    int gw = blockIdx.x * 4 + (int)(threadIdx.x >> 6);
    int lane = threadIdx.x & 63;
    int b = gw / CAP, i = gw - b * CAP;
    if (i >= cnt[b]) return;
    int v = lst[b * CAP + i];
    float bv = b0[lane];
    float m0 = wsum64(bv) * (1.0f / DD);
    float c0 = bv - m0;
    float v0 = wsum64(c0 * c0) * (1.0f / DD);
    float dv = bf2f(f2bf_rne(
        fmaxf(c0 * rsqrtf(v0 + 1e-5f) * g0[lane] + be0[lane], 0.0f)));
    const float* rb = rel_buf + b * RR * DD;
    int h0 = bt[b * KK * 3];
    int beg = v * CAPDEG, end = beg + min(deg[v], CAPDEG);
    float ac = 0.0f, ar = 0.0f;
    for (int j = beg; j < end; ++j) {
        int p = pack[j];
        int s = p & 0xFFFF;
        float r = rb[(p >> 16) * DD + lane];
        if ((fixbit[s >> 5] >> (s & 31)) & 1)
            ac += bf2f(xin[((size_t)s * BB + b) * DD + lane]) * r;
        else
            ar += r;
    }
    float av = ac + dv * ar;
    if (v == h0) av += query[b * DD + lane];
    bool fx = (fixbit[v >> 5] >> (v & 31)) & 1;
    float xv = fx ? bf2f(xin[((size_t)v * BB + b) * DD + lane]) : dv;
    float acc = bias[lane];
#pragma unroll 8
    for (int k = 0; k < DD; ++k) {
        acc += __shfl(xv, k, 64) * W[k * DD + lane];
        acc += __shfl(av, k, 64) * W[(DD + k) * DD + lane];
    }
    float m = wsum64(acc) * (1.0f / DD);
    float c = acc - m;
    float vv = wsum64(c * c) * (1.0f / DD);
    float o = c * rsqrtf(vv + 1e-5f) * g[lane] + beta[lane];
    xout[((size_t)v * BB + b) * DD + lane] = f2bf_rne(fmaxf(o, 0.0f) + xv);
}

// ==================== readout ================================================
__global__ __launch_bounds__(128) void readout(
    const int* __restrict__ bt, const unsigned short* __restrict__ x_bfi,
    const float* __restrict__ query,
    const float* __restrict__ W1, const float* __restrict__ b1,
    const float* __restrict__ W2, const float* __restrict__ b2,
    float* __restrict__ out)
{
    int b = blockIdx.x / KK, k = blockIdx.x - b * KK;
    int t = bt[(b * KK + k) * 3 + 1];
    __shared__ float feat[2 * DD];
    __shared__ float red[2 * DD];
    int j = threadIdx.x;
    if (j < DD) feat[j] = bf2f(x_bfi[((size_t)t * BB + b) * DD + j]);
    else        feat[j] = query[b * DD + (j - DD)];
    __syncthreads();
    float h = b1[j];
#pragma unroll 8
    for (int i = 0; i < 2 * DD; ++i) h += feat[i] * W1[i * 2 * DD + j];
    h = fmaxf(h, 0.0f);
    red[j] = h * W2[j];
    __syncthreads();
    for (int s = 64; s > 0; s >>= 1) {
        if (j < s) red[j] += red[j + s];
        __syncthreads();
    }
    if (j == 0) out[blockIdx.x] = red[0] + b2[0];
}

extern "C" void kernel_launch(void* const* d_in, const int* in_sizes, int n_in,
                              void* d_out, int out_size, void* d_ws, size_t ws_size,
                              hipStream_t stream) {
    const int*   edge_index     = (const int*)d_in[0];
    const int*   edge_type      = (const int*)d_in[1];
    const int*   rel_edge_index = (const int*)d_in[2];
    const int*   rel_edge_type  = (const int*)d_in[3];
    const int*   batch_triples  = (const int*)d_in[4];
    const float* rel_emb        = (const float*)d_in[5];
    const float* rel_W          = (const float*)d_in[6];
    const float* rel_b          = (const float*)d_in[7];
    const float* rel_g          = (const float*)d_in[8];
    const float* rel_beta       = (const float*)d_in[9];
    const float* proj_W1        = (const float*)d_in[10];
    const float* proj_b1        = (const float*)d_in[11];
    const float* proj_W2        = (const float*)d_in[12];
    const float* proj_b2        = (const float*)d_in[13];
    const float* ent_W          = (const float*)d_in[14];
    const float* ent_b          = (const float*)d_in[15];
    const float* ent_g          = (const float*)d_in[16];
    const float* ent_beta       = (const float*)d_in[17];
    const float* mlp_W1         = (const float*)d_in[18];
    const float* mlp_b1         = (const float*)d_in[19];
    const float* mlp_W2         = (const float*)d_in[20];
    const float* mlp_b2         = (const float*)d_in[21];

    float* ws = (float*)d_ws;
    float* xrel0    = ws;                                   // B*R*D
    float* xrel1    = xrel0    + BB * RR * DD;              // B*R*D
    float* rel_buf4 = xrel1    + BB * RR * DD;              // 4*B*R*D
    float* query    = rel_buf4 + 4 * BB * RR * DD;          // B*D
    // --- zeroed region (one memset) ---
    int*      deg    = (int*)(query + BB * DD);             // NN
    int*      rdeg   = deg + NN;                            // RR
    unsigned* fixbit = (unsigned*)(rdeg + RR);              // NFB
    unsigned* bm3    = fixbit + NFB;                        // BB*NFB
    unsigned* bm2    = bm3 + BB * NFB;                      // BB*NFB
    unsigned* bm1    = bm2 + BB * NFB;                      // BB*NFB
    int*      cnt3   = (int*)(bm1 + BB * NFB);              // BB
    int*      cnt2   = cnt3 + BB;                           // BB
    int*      cnt1   = cnt2 + BB;                           // BB
    int*      fixcnt = cnt1 + BB;                           // BB
    const size_t ZN  = (size_t)NN + RR + NFB + 3 * BB * NFB + 4 * BB;
    // --- end zeroed region ---
    int* pack    = fixcnt + BB;                             // NN*CAPDEG
    int* rpack   = pack + (size_t)NN * CAPDEG;              // RR*RCAP
    int* fixlist = rpack + RR * RCAP;                       // BB*FCAP
    int* lst3    = fixlist + BB * FCAP;                     // BB*S3CAP
    int* lst2    = lst3 + BB * S3CAP;                       // BB*S2CAP
    int* lst1    = lst2 + BB * S2CAP;                       // BB*S1CAP
    uintptr_t wp = (uintptr_t)(lst1 + BB * S1CAP);
    wp = (wp + 15) & ~(uintptr_t)15;
    unsigned short* x_bfiA = (unsigned short*)wp;           // B*N*D bf16 [v][b][d]
    unsigned short* x_bfiB = x_bfiA + (size_t)BB * NN * DD; // B*N*D bf16 [v][b][d]

    // ---- zero counters/bitmaps; one fused edge pass builds everything ----
    hipMemsetAsync(deg, 0, sizeof(int) * ZN, stream);
    edge_scan<<<NEB + (ERE + 255) / 256, 256, 0, stream>>>(
        edge_index, edge_type, batch_triples,
        deg, pack, fixlist, fixcnt, fixbit,
        bm3, lst3, cnt3,
        rel_edge_index, rel_edge_type, rdeg, rpack);

    // ---- frontier: S2 = S3 ∪ N(S3); S1 = S2 ∪ N(S2) ----
    fr_expand<<<BB * S3CAP / 4, 256, 0, stream>>>(
        deg, pack, lst3, cnt3, S3CAP, bm2, lst2, cnt2, S2CAP);
    fr_expand<<<BB * S2CAP / 4, 256, 0, stream>>>(
        deg, pack, lst2, cnt2, S2CAP, bm1, lst1, cnt1, S1CAP);

    // ---- relation stage (4 launches; last fuses proj + query) ----
    rel_layer0<<<BB * RR / 4, 256, 0, stream>>>(
        rdeg, rpack, batch_triples, rel_emb,
        rel_W, rel_b, rel_g, rel_beta, xrel1);
    rel_layer<<<BB * RR / 4, 256, 0, stream>>>(
        rdeg, rpack, batch_triples, rel_emb + 1 * RT * DD,
        rel_W + 1 * 2 * DD * DD, rel_b + 1 * DD,
        rel_g + 1 * DD, rel_beta + 1 * DD, xrel1, xrel0);
    rel_layer<<<BB * RR / 4, 256, 0, stream>>>(
        rdeg, rpack, batch_triples, rel_emb + 2 * RT * DD,
        rel_W + 2 * 2 * DD * DD, rel_b + 2 * DD,
        rel_g + 2 * DD, rel_beta + 2 * DD, xrel0, xrel1);
    rel_layer3_proj<<<BB * RR / 4, 256, 0, stream>>>(
        rdeg, rpack, batch_triples, rel_emb + 3 * RT * DD,
        rel_W + 3 * 2 * DD * DD, rel_b + 3 * DD,
        rel_g + 3 * DD, rel_beta + 3 * DD, xrel1,
        proj_W1, proj_b1, proj_W2, proj_b2, rel_buf4, query);

    // ---- entity layer 0: seed union-fixset rows + exact fix rows ----
    l0_seed<<<(BB * FCAP) / 4, 256, 0, stream>>>(
        fixlist, fixcnt, ent_b, ent_g, ent_beta, x_bfiA);
    l0_fix<<<(BB * FCAP) / 4, 256, 0, stream>>>(
        batch_triples, fixlist, fixcnt, query, rel_buf4,
        ent_W, ent_b, ent_g, ent_beta, x_bfiA);

    // ---- entity layers 1..3 on shrinking frontiers ----
    list_layer_l1<<<BB * S1CAP / 4, 256, 0, stream>>>(
        deg, pack, batch_triples, fixbit, lst1, cnt1, S1CAP,
        x_bfiA, rel_buf4 + 1 * BB * RR * DD, query,
        ent_W + 1 * 2 * DD * DD, ent_b + 1 * DD, ent_g + 1 * DD,
        ent_beta + 1 * DD, ent_b, ent_g, ent_beta, x_bfiB);
    list_layer<<<BB * S2CAP / 4, 256, 0, stream>>>(
        deg, pack, batch_triples, lst2, cnt2, S2CAP,
        x_bfiB, rel_buf4 + 2 * BB * RR * DD, query,
        ent_W + 2 * 2 * DD * DD, ent_b + 2 * DD, ent_g + 2 * DD,
        ent_beta + 2 * DD, x_bfiA);
    list_layer<<<BB * S3CAP / 4, 256, 0, stream>>>(
        deg, pack, batch_triples, lst3, cnt3, S3CAP,
        x_bfiA, rel_buf4 + 3 * BB * RR * DD, query,
        ent_W + 3 * 2 * DD * DD, ent_b + 3 * DD, ent_g + 3 * DD,
        ent_beta + 3 * DD, x_bfiB);

    readout<<<BB * KK, 2 * DD, 0, stream>>>(batch_triples, x_bfiB, query,
                                            mlp_W1, mlp_b1, mlp_W2, mlp_b2,
                                            (float*)d_out);
}

// Round 19
// 140.655 us; speedup vs baseline: 2.2984x; 1.3302x over previous
//
#include <hip/hip_runtime.h>
#include <hip/hip_bf16.h>

#define BB 4
#define KK 16
#define NN 50000
#define EE 300000
#define RR 64
#define ERE 2048
#define RT 4
#define DD 64
#define LL 4
#define FCAP 256
#define NFB 1568   // bitmap ints, >= (NN+31)/32
#define S3CAP 16
#define S2CAP 1024
#define S1CAP 4096
#define CAPDEG 64  // fixed-slot CSR width
#define RCAP 128   // rel-graph slot width
#define NEB 1172   // (EE+255)/256 entity-edge blocks

typedef float f32x4 __attribute__((ext_vector_type(4)));

__device__ __forceinline__ float wsum64(float v) {
#pragma unroll
    for (int off = 32; off > 0; off >>= 1) v += __shfl_xor(v, off, 64);
    return v;
}

__device__ __forceinline__ unsigned short f2bf_rne(float f) {
    unsigned u = __builtin_bit_cast(unsigned, f);
    return (unsigned short)((u + 0x7FFFu + ((u >> 16) & 1u)) >> 16);
}

__device__ __forceinline__ float bf2f(unsigned short h) {
    unsigned u = ((unsigned)h) << 16;
    return __builtin_bit_cast(float, u);
}

// ==== one fused edge pass: slot-CSR + fixlist/bitmap + S3 init + rel-CSR ====
__global__ __launch_bounds__(256) void edge_scan(
    const int* __restrict__ edge_index, const int* __restrict__ edge_type,
    const int* __restrict__ bt,
    int* __restrict__ deg, int* __restrict__ pack,
    int* __restrict__ fixlist, int* __restrict__ fixcnt,
    unsigned* __restrict__ fixbit,
    unsigned* __restrict__ bm3, int* __restrict__ lst3, int* __restrict__ cnt3,
    const int* __restrict__ rel_edge_index, const int* __restrict__ rel_edge_type,
    int* __restrict__ rdeg, int* __restrict__ rpack)
{
    int gid = blockIdx.x;
    if (gid >= NEB) {  // rel-graph edges
        int e = (gid - NEB) * 256 + threadIdx.x;
        if (e < ERE) {
            int s = rel_edge_index[e];
            int d = rel_edge_index[ERE + e];
            int ty = rel_edge_type[e];
            int slot = atomicAdd(&rdeg[d], 1);
            if (slot < RCAP) rpack[d * RCAP + slot] = s | (ty << 16);
        }
        return;
    }
    int e = gid * 256 + threadIdx.x;
    if (e < BB * KK) {  // S3 frontier init (targets)
        int b = e / KK, k = e - b * KK;
        int t = bt[(b * KK + k) * 3 + 1];
        unsigned old = atomicOr(&bm3[b * NFB + (t >> 5)], 1u << (t & 31));
        if (!((old >> (t & 31)) & 1)) {
            int pos = atomicAdd(&cnt3[b], 1);
            if (pos < S3CAP) lst3[b * S3CAP + pos] = t;
        }
    }
    if (e < BB) {  // h0 self-marker for layer-0 fixlist
        int h0 = bt[e * KK * 3];
        int pos = atomicAdd(&fixcnt[e], 1);
        if (pos < FCAP) fixlist[e * FCAP + pos] = h0 | (int)(0xFFFFu << 16);
        atomicOr(&fixbit[h0 >> 5], 1u << (h0 & 31));
    }
    if (e >= EE) return;
    int s = edge_index[e];
    int d = edge_index[EE + e];
    int t = edge_type[e];
    int slot = atomicAdd(&deg[d], 1);
    if (slot < CAPDEG) pack[(size_t)d * CAPDEG + slot] = s | (t << 16);
#pragma unroll
    for (int b = 0; b < BB; ++b) {
        int h0 = bt[b * KK * 3];
        if (s == h0) {
            int pos = atomicAdd(&fixcnt[b], 1);
            if (pos < FCAP) fixlist[b * FCAP + pos] = d | (t << 16);
            atomicOr(&fixbit[d >> 5], 1u << (d & 31));
        }
    }
}

// ==================== frontier expansion =====================================
__global__ __launch_bounds__(256) void fr_expand(
    const int* __restrict__ deg, const int* __restrict__ pack,
    const int* __restrict__ lstIn, const int* __restrict__ cntIn, int INCAP,
    unsigned* __restrict__ bmOut, int* __restrict__ lstOut,
    int* __restrict__ cntOut, int OUTCAP)
{
    int gw = blockIdx.x * 4 + (int)(threadIdx.x >> 6);
    int lane = threadIdx.x & 63;
    int b = gw / INCAP, idx = gw - b * INCAP;
    if (idx >= cntIn[b]) return;
    int v = lstIn[b * INCAP + idx];
    if (lane == 0) {
        unsigned old = atomicOr(&bmOut[b * NFB + (v >> 5)], 1u << (v & 31));
        if (!((old >> (v & 31)) & 1)) {
            int pos = atomicAdd(&cntOut[b], 1);
            if (pos < OUTCAP) lstOut[b * OUTCAP + pos] = v;
        }
    }
    int beg = v * CAPDEG, end = beg + min(deg[v], CAPDEG);
    for (int j = beg + lane; j < end; j += 64) {
        int s = pack[j] & 0xFFFF;
        unsigned old = atomicOr(&bmOut[b * NFB + (s >> 5)], 1u << (s & 31));
        if (!((old >> (s & 31)) & 1)) {
            int pos = atomicAdd(&cntOut[b], 1);
            if (pos < OUTCAP) lstOut[b * OUTCAP + pos] = s;
        }
    }
}

// ============ relation conv layer: one block per row, k-split 4 waves ========
__global__ __launch_bounds__(256) void rel_layer_ks(
    const int* __restrict__ rdeg, const int* __restrict__ rpack,
    const int* __restrict__ bt, const float* __restrict__ emb,
    const float* __restrict__ W, const float* __restrict__ bias,
    const float* __restrict__ g, const float* __restrict__ beta,
    const float* __restrict__ xin,  // null semantics via layer0 flag
    float* __restrict__ xout, int layer0)
{
    __shared__ float xs[DD], as[DD], part[4][DD];
    int row = blockIdx.x;              // 0..BB*RR-1
    int wid = (int)(threadIdx.x >> 6);
    int lane = threadIdx.x & 63;
    int b = row >> 6, r = row & 63;
    int r0 = bt[(b * KK) * 3 + 2];
    float xv = layer0 ? ((r == r0) ? 1.0f : 0.0f) : xin[row * DD + lane];
    if (wid == 0) xs[lane] = xv;
    int beg = r * RCAP, end = beg + min(rdeg[r], RCAP);
    float av = 0.0f;
    if (layer0) {
        for (int j = beg + wid; j < end; j += 4) {
            int p = rpack[j];
            if ((p & 0xFFFF) == r0) av += emb[(p >> 16) * DD + lane];
        }
    } else {
        const float* xb = xin + b * RR * DD;
        for (int j = beg + wid; j < end; j += 4) {
            int p = rpack[j];
            av += xb[(p & 0xFFFF) * DD + lane] * emb[(p >> 16) * DD + lane];
        }
    }
    part[wid][lane] = av;
    __syncthreads();
    if (wid == 0)
        as[lane] = part[0][lane] + part[1][lane] + part[2][lane] + part[3][lane]
                   + ((r == r0) ? 1.0f : 0.0f);
    __syncthreads();
    // dense k-split: waves 0,1 -> x half; waves 2,3 -> agg half
    const float* src = (wid < 2) ? (xs + wid * 32) : (as + (wid - 2) * 32);
    const float* Wp  = (wid < 2) ? (W + (wid * 32) * DD)
                                 : (W + (DD + (wid - 2) * 32) * DD);
    float acc = 0.0f;
#pragma unroll 8
    for (int i = 0; i < 32; ++i) acc += src[i] * Wp[i * DD + lane];
    part[wid][lane] = acc;
    __syncthreads();
    if (wid == 0) {
        float a = bias[lane] + part[0][lane] + part[1][lane]
                             + part[2][lane] + part[3][lane];
        float m = wsum64(a) * (1.0f / DD);
        float c = a - m;
        float v = wsum64(c * c) * (1.0f / DD);
        float o = c * rsqrtf(v + 1e-5f) * g[lane] + beta[lane];
        xout[row * DD + lane] = fmaxf(o, 0.0f) + xs[lane];
    }
}

// ======= projection: one block per (layer,row), k-split; query at l==0 =======
__global__ __launch_bounds__(256) void rel_proj_ks(
    const float* __restrict__ rel_repr, const int* __restrict__ bt,
    const float* __restrict__ pW1, const float* __restrict__ pb1,
    const float* __restrict__ pW2, const float* __restrict__ pb2,
    float* __restrict__ rel_buf4, float* __restrict__ query)
{
    __shared__ float rs[DD], hs[DD], part[4][DD];
    int gb = blockIdx.x;               // l*BB*RR + row
    int l = gb / (BB * RR), row = gb - l * (BB * RR);
    int wid = (int)(threadIdx.x >> 6);
    int lane = threadIdx.x & 63;
    float res = rel_repr[row * DD + lane];
    if (wid == 0) rs[lane] = res;
    __syncthreads();
    const float* w1 = pW1 + l * DD * DD;
    float h = 0.0f;
#pragma unroll
    for (int i = 0; i < 16; ++i) {
        int k = wid * 16 + i;
        h += rs[k] * w1[k * DD + lane];
    }
    part[wid][lane] = h;
    __syncthreads();
    if (wid == 0) {
        float hh = pb1[l * DD + lane] + part[0][lane] + part[1][lane]
                                      + part[2][lane] + part[3][lane];
        hs[lane] = fmaxf(hh, 0.0f);
    }
    __syncthreads();
    const float* w2 = pW2 + l * DD * DD;
    float o = 0.0f;
#pragma unroll
    for (int i = 0; i < 16; ++i) {
        int k = wid * 16 + i;
        o += hs[k] * w2[k * DD + lane];
    }
    part[wid][lane] = o;
    __syncthreads();
    if (wid == 0) {
        float oo = pb2[l * DD + lane] + part[0][lane] + part[1][lane]
                                      + part[2][lane] + part[3][lane];
        rel_buf4[(size_t)gb * DD + lane] = oo;
        int b = row >> 6, r = row & 63;
        int r0 = bt[(b * KK) * 3 + 2];
        if (l == 0 && r == r0) query[b * DD + lane] = rs[lane];
    }
}

// ==================== entity stage layer 0 (sparse) ==========================
__global__ __launch_bounds__(256) void l0_seed(
    const int* __restrict__ fixlist, const int* __restrict__ cnt,
    const float* __restrict__ b0, const float* __restrict__ g0,
    const float* __restrict__ be0, unsigned short* __restrict__ x_bfi)
{
    int gidx = blockIdx.x * 4 + (int)(threadIdx.x >> 6);
    int lane = threadIdx.x & 63;
    float bv = b0[lane];
    float m = wsum64(bv) * (1.0f / DD);
    float c = bv - m;
    float v = wsum64(c * c) * (1.0f / DD);
    float dvec = fmaxf(c * rsqrtf(v + 1e-5f) * g0[lane] + be0[lane], 0.0f);
    int bl = gidx / FCAP, i = gidx - bl * FCAP;
    int nc = min(cnt[bl], FCAP);
    if (i >= nc) return;
    int vx = fixlist[bl * FCAP + i] & 0xFFFF;
    int b = lane >> 4, d0 = (lane & 15) * 4;
    ushort4 o;
    o.x = f2bf_rne(__shfl(dvec, d0 + 0, 64));
    o.y = f2bf_rne(__shfl(dvec, d0 + 1, 64));
    o.z = f2bf_rne(__shfl(dvec, d0 + 2, 64));
    o.w = f2bf_rne(__shfl(dvec, d0 + 3, 64));
    *(ushort4*)&x_bfi[((size_t)vx * BB + b) * DD + d0] = o;
}

__global__ __launch_bounds__(256) void l0_fix(
    const int* __restrict__ bt, const int* __restrict__ fixlist,
    const int* __restrict__ cnt, const float* __restrict__ query,
    const float* __restrict__ rel_buf,
    const float* __restrict__ W0, const float* __restrict__ b0,
    const float* __restrict__ g0, const float* __restrict__ be0,
    unsigned short* __restrict__ x_bfi)
{
    int gidx = blockIdx.x * 4 + (threadIdx.x >> 6);
    int lane = threadIdx.x & 63;
    int b = gidx / FCAP, i = gidx - b * FCAP;
    int nc = min(cnt[b], FCAP);
    if (i >= nc) return;
    unsigned ent = (unsigned)fixlist[b * FCAP + i];
    int v = (int)(ent & 0xFFFFu);
    int h0 = bt[b * KK * 3];
    float q = query[b * DD + lane];
    float agg = (v == h0) ? q : 0.0f;
    for (int j = 0; j < nc; ++j) {
        unsigned ej = (unsigned)fixlist[b * FCAP + j];
        if ((int)(ej & 0xFFFFu) == v) {
            unsigned et = ej >> 16;
            if (et != 0xFFFFu)
                agg += q * rel_buf[(b * RR + (int)et) * DD + lane];
        }
    }
    float xr = (v == h0) ? q : 0.0f;
    float acc = b0[lane];
#pragma unroll 8
    for (int k = 0; k < DD; ++k) {
        acc += __shfl(xr, k, 64) * W0[k * DD + lane];
        acc += __shfl(agg, k, 64) * W0[(DD + k) * DD + lane];
    }
    float m = wsum64(acc) * (1.0f / DD);
    float c = acc - m;
    float vv = wsum64(c * c) * (1.0f / DD);
    float res = fmaxf(c * rsqrtf(vv + 1e-5f) * g0[lane] + be0[lane], 0.0f) + xr;
    x_bfi[((size_t)v * BB + b) * DD + lane] = f2bf_rne(res);
}

// ==================== list-based conv layer (layers 2,3) =====================
__global__ __launch_bounds__(256) void list_layer(
    const int* __restrict__ deg, const int* __restrict__ pack,
    const int* __restrict__ bt,
    const int* __restrict__ lst, const int* __restrict__ cnt, int CAP,
    const unsigned short* __restrict__ xin,
    const float* __restrict__ rel_buf, const float* __restrict__ query,
    const float* __restrict__ W, const float* __restrict__ bias,
    const float* __restrict__ g, const float* __restrict__ beta,
    unsigned short* __restrict__ xout)
{
    int gw = blockIdx.x * 4 + (int)(threadIdx.x >> 6);
    int lane = threadIdx.x & 63;
    int b = gw / CAP, i = gw - b * CAP;
    if (i >= cnt[b]) return;
    int v = lst[b * CAP + i];
    const float* rb = rel_buf + b * RR * DD;
    int h0 = bt[b * KK * 3];
    int beg = v * CAPDEG, end = beg + min(deg[v], CAPDEG);
    float av = 0.0f;
    int j = beg;
    for (; j + 1 < end; j += 2) {
        int p0 = pack[j], p1 = pack[j + 1];
        float x0 = bf2f(xin[((size_t)(p0 & 0xFFFF) * BB + b) * DD + lane]);
        float x1 = bf2f(xin[((size_t)(p1 & 0xFFFF) * BB + b) * DD + lane]);
        float r0 = rb[(p0 >> 16) * DD + lane];
        float r1 = rb[(p1 >> 16) * DD + lane];
        av += x0 * r0 + x1 * r1;
    }
    if (j < end) {
        int p0 = pack[j];
        av += bf2f(xin[((size_t)(p0 & 0xFFFF) * BB + b) * DD + lane])
              * rb[(p0 >> 16) * DD + lane];
    }
    if (v == h0) av += query[b * DD + lane];
    float xv = bf2f(xin[((size_t)v * BB + b) * DD + lane]);
    float acc = bias[lane];
#pragma unroll 8
    for (int k = 0; k < DD; ++k) {
        acc += __shfl(xv, k, 64) * W[k * DD + lane];
        acc += __shfl(av, k, 64) * W[(DD + k) * DD + lane];
    }
    float m = wsum64(acc) * (1.0f / DD);
    float c = acc - m;
    float vv = wsum64(c * c) * (1.0f / DD);
    float o = c * rsqrtf(vv + 1e-5f) * g[lane] + beta[lane];
    xout[((size_t)v * BB + b) * DD + lane] = f2bf_rne(fmaxf(o, 0.0f) + xv);
}

// ==================== list-based layer 1 (constant fast path) ================
__global__ __launch_bounds__(256) void list_layer_l1(
    const int* __restrict__ deg, const int* __restrict__ pack,
    const int* __restrict__ bt, const unsigned* __restrict__ fixbit,
    const int* __restrict__ lst, const int* __restrict__ cnt, int CAP,
    const unsigned short* __restrict__ xin,
    const float* __restrict__ rel_buf, const float* __restrict__ query,
    const float* __restrict__ W, const float* __restrict__ bias,
    const float* __restrict__ g, const float* __restrict__ beta,
    const float* __restrict__ b0, const float* __restrict__ g0,
    const float* __restrict__ be0,
    unsigned short* __restrict__ xout)
{
    int gw = blockIdx.x * 4 + (int)(threadIdx.x >> 6);
    int lane = threadIdx.x & 63;
    int b = gw / CAP, i = gw - b * CAP;
    if (i >= cnt[b]) return;
    int v = lst[b * CAP + i];
    float bv = b0[lane];
    float m0 = wsum64(bv) * (1.0f / DD);
    float c0 = bv - m0;
    float v0 = wsum64(c0 * c0) * (1.0f / DD);
    float dv = bf2f(f2bf_rne(
        fmaxf(c0 * rsqrtf(v0 + 1e-5f) * g0[lane] + be0[lane], 0.0f)));
    const float* rb = rel_buf + b * RR * DD;
    int h0 = bt[b * KK * 3];
    int beg = v * CAPDEG, end = beg + min(deg[v], CAPDEG);
    float ac = 0.0f, ar = 0.0f;
    for (int j = beg; j < end; ++j) {
        int p = pack[j];
        int s = p & 0xFFFF;
        float r = rb[(p >> 16) * DD + lane];
        if ((fixbit[s >> 5] >> (s & 31)) & 1)
            ac += bf2f(xin[((size_t)s * BB + b) * DD + lane]) * r;
        else
            ar += r;
    }
    float av = ac + dv * ar;
    if (v == h0) av += query[b * DD + lane];
    bool fx = (fixbit[v >> 5] >> (v & 31)) & 1;
    float xv = fx ? bf2f(xin[((size_t)v * BB + b) * DD + lane]) : dv;
    float acc = bias[lane];
#pragma unroll 8
    for (int k = 0; k < DD; ++k) {
        acc += __shfl(xv, k, 64) * W[k * DD + lane];
        acc += __shfl(av, k, 64) * W[(DD + k) * DD + lane];
    }
    float m = wsum64(acc) * (1.0f / DD);
    float c = acc - m;
    float vv = wsum64(c * c) * (1.0f / DD);
    float o = c * rsqrtf(vv + 1e-5f) * g[lane] + beta[lane];
    xout[((size_t)v * BB + b) * DD + lane] = f2bf_rne(fmaxf(o, 0.0f) + xv);
}

// ==================== readout ================================================
__global__ __launch_bounds__(128) void readout(
    const int* __restrict__ bt, const unsigned short* __restrict__ x_bfi,
    const float* __restrict__ query,
    const float* __restrict__ W1, const float* __restrict__ b1,
    const float* __restrict__ W2, const float* __restrict__ b2,
    float* __restrict__ out)
{
    int b = blockIdx.x / KK, k = blockIdx.x - b * KK;
    int t = bt[(b * KK + k) * 3 + 1];
    __shared__ float feat[2 * DD];
    __shared__ float red[2 * DD];
    int j = threadIdx.x;
    if (j < DD) feat[j] = bf2f(x_bfi[((size_t)t * BB + b) * DD + j]);
    else        feat[j] = query[b * DD + (j - DD)];
    __syncthreads();
    float h = b1[j];
#pragma unroll 8
    for (int i = 0; i < 2 * DD; ++i) h += feat[i] * W1[i * 2 * DD + j];
    h = fmaxf(h, 0.0f);
    red[j] = h * W2[j];
    __syncthreads();
    for (int s = 64; s > 0; s >>= 1) {
        if (j < s) red[j] += red[j + s];
        __syncthreads();
    }
    if (j == 0) out[blockIdx.x] = red[0] + b2[0];
}

extern "C" void kernel_launch(void* const* d_in, const int* in_sizes, int n_in,
                              void* d_out, int out_size, void* d_ws, size_t ws_size,
                              hipStream_t stream) {
    const int*   edge_index     = (const int*)d_in[0];
    const int*   edge_type      = (const int*)d_in[1];
    const int*   rel_edge_index = (const int*)d_in[2];
    const int*   rel_edge_type  = (const int*)d_in[3];
    const int*   batch_triples  = (const int*)d_in[4];
    const float* rel_emb        = (const float*)d_in[5];
    const float* rel_W          = (const float*)d_in[6];
    const float* rel_b          = (const float*)d_in[7];
    const float* rel_g          = (const float*)d_in[8];
    const float* rel_beta       = (const float*)d_in[9];
    const float* proj_W1        = (const float*)d_in[10];
    const float* proj_b1        = (const float*)d_in[11];
    const float* proj_W2        = (const float*)d_in[12];
    const float* proj_b2        = (const float*)d_in[13];
    const float* ent_W          = (const float*)d_in[14];
    const float* ent_b          = (const float*)d_in[15];
    const float* ent_g          = (const float*)d_in[16];
    const float* ent_beta       = (const float*)d_in[17];
    const float* mlp_W1         = (const float*)d_in[18];
    const float* mlp_b1         = (const float*)d_in[19];
    const float* mlp_W2         = (const float*)d_in[20];
    const float* mlp_b2         = (const float*)d_in[21];

    float* ws = (float*)d_ws;
    float* xrel0    = ws;                                   // B*R*D
    float* xrel1    = xrel0    + BB * RR * DD;              // B*R*D
    float* rel_buf4 = xrel1    + BB * RR * DD;              // 4*B*R*D
    float* query    = rel_buf4 + 4 * BB * RR * DD;          // B*D
    // --- zeroed region (one memset) ---
    int*      deg    = (int*)(query + BB * DD);             // NN
    int*      rdeg   = deg + NN;                            // RR
    unsigned* fixbit = (unsigned*)(rdeg + RR);              // NFB
    unsigned* bm3    = fixbit + NFB;                        // BB*NFB
    unsigned* bm2    = bm3 + BB * NFB;                      // BB*NFB
    unsigned* bm1    = bm2 + BB * NFB;                      // BB*NFB
    int*      cnt3   = (int*)(bm1 + BB * NFB);              // BB
    int*      cnt2   = cnt3 + BB;                           // BB
    int*      cnt1   = cnt2 + BB;                           // BB
    int*      fixcnt = cnt1 + BB;                           // BB
    const size_t ZN  = (size_t)NN + RR + NFB + 3 * BB * NFB + 4 * BB;
    // --- end zeroed region ---
    int* pack    = fixcnt + BB;                             // NN*CAPDEG
    int* rpack   = pack + (size_t)NN * CAPDEG;              // RR*RCAP
    int* fixlist = rpack + RR * RCAP;                       // BB*FCAP
    int* lst3    = fixlist + BB * FCAP;                     // BB*S3CAP
    int* lst2    = lst3 + BB * S3CAP;                       // BB*S2CAP
    int* lst1    = lst2 + BB * S2CAP;                       // BB*S1CAP
    uintptr_t wp = (uintptr_t)(lst1 + BB * S1CAP);
    wp = (wp + 15) & ~(uintptr_t)15;
    unsigned short* x_bfiA = (unsigned short*)wp;           // B*N*D bf16 [v][b][d]
    unsigned short* x_bfiB = x_bfiA + (size_t)BB * NN * DD; // B*N*D bf16 [v][b][d]

    // ---- zero counters/bitmaps; one fused edge pass builds everything ----
    hipMemsetAsync(deg, 0, sizeof(int) * ZN, stream);
    edge_scan<<<NEB + (ERE + 255) / 256, 256, 0, stream>>>(
        edge_index, edge_type, batch_triples,
        deg, pack, fixlist, fixcnt, fixbit,
        bm3, lst3, cnt3,
        rel_edge_index, rel_edge_type, rdeg, rpack);

    // ---- frontier: S2 = S3 ∪ N(S3); S1 = S2 ∪ N(S2) ----
    fr_expand<<<BB * S3CAP / 4, 256, 0, stream>>>(
        deg, pack, lst3, cnt3, S3CAP, bm2, lst2, cnt2, S2CAP);
    fr_expand<<<BB * S2CAP / 4, 256, 0, stream>>>(
        deg, pack, lst2, cnt2, S2CAP, bm1, lst1, cnt1, S1CAP);

    // ---- relation stage: k-split conv layers + parallel projection ----
    rel_layer_ks<<<BB * RR, 256, 0, stream>>>(
        rdeg, rpack, batch_triples, rel_emb,
        rel_W, rel_b, rel_g, rel_beta, nullptr, xrel1, 1);
    rel_layer_ks<<<BB * RR, 256, 0, stream>>>(
        rdeg, rpack, batch_triples, rel_emb + 1 * RT * DD,
        rel_W + 1 * 2 * DD * DD, rel_b + 1 * DD,
        rel_g + 1 * DD, rel_beta + 1 * DD, xrel1, xrel0, 0);
    rel_layer_ks<<<BB * RR, 256, 0, stream>>>(
        rdeg, rpack, batch_triples, rel_emb + 2 * RT * DD,
        rel_W + 2 * 2 * DD * DD, rel_b + 2 * DD,
        rel_g + 2 * DD, rel_beta + 2 * DD, xrel0, xrel1, 0);
    rel_layer_ks<<<BB * RR, 256, 0, stream>>>(
        rdeg, rpack, batch_triples, rel_emb + 3 * RT * DD,
        rel_W + 3 * 2 * DD * DD, rel_b + 3 * DD,
        rel_g + 3 * DD, rel_beta + 3 * DD, xrel1, xrel0, 0);
    rel_proj_ks<<<LL * BB * RR, 256, 0, stream>>>(
        xrel0, batch_triples, proj_W1, proj_b1, proj_W2, proj_b2,
        rel_buf4, query);

    // ---- entity layer 0: seed union-fixset rows + exact fix rows ----
    l0_seed<<<(BB * FCAP) / 4, 256, 0, stream>>>(
        fixlist, fixcnt, ent_b, ent_g, ent_beta, x_bfiA);
    l0_fix<<<(BB * FCAP) / 4, 256, 0, stream>>>(
        batch_triples, fixlist, fixcnt, query, rel_buf4,
        ent_W, ent_b, ent_g, ent_beta, x_bfiA);

    // ---- entity layers 1..3 on shrinking frontiers ----
    list_layer_l1<<<BB * S1CAP / 4, 256, 0, stream>>>(
        deg, pack, batch_triples, fixbit, lst1, cnt1, S1CAP,
        x_bfiA, rel_buf4 + 1 * BB * RR * DD, query,
        ent_W + 1 * 2 * DD * DD, ent_b + 1 * DD, ent_g + 1 * DD,
        ent_beta + 1 * DD, ent_b, ent_g, ent_beta, x_bfiB);
    list_layer<<<BB * S2CAP / 4, 256, 0, stream>>>(
        deg, pack, batch_triples, lst2, cnt2, S2CAP,
        x_bfiB, rel_buf4 + 2 * BB * RR * DD, query,
        ent_W + 2 * 2 * DD * DD, ent_b + 2 * DD, ent_g + 2 * DD,
        ent_beta + 2 * DD, x_bfiA);
    list_layer<<<BB * S3CAP / 4, 256, 0, stream>>>(
        deg, pack, batch_triples, lst3, cnt3, S3CAP,
        x_bfiA, rel_buf4 + 3 * BB * RR * DD, query,
        ent_W + 3 * 2 * DD * DD, ent_b + 3 * DD, ent_g + 3 * DD,
        ent_beta + 3 * DD, x_bfiB);

    readout<<<BB * KK, 2 * DD, 0, stream>>>(batch_triples, x_bfiB, query,
                                            mlp_W1, mlp_b1, mlp_W2, mlp_b2,
                                            (float*)d_out);
}